// Round 1
// baseline (3206.718 us; speedup 1.0000x reference)
//
#include <hip/hip_runtime.h>
#include <math.h>

#define D 256
#define NHD 8
#define HDIM 32
#define NPTS 4
#define NLAY 6
#define FFD 1024
#define BSZ 4
#define NSRC 9216
#define NQ 300
#define NROWS (BSZ*NQ)      // 1200
#define NVROWS (BSZ*NSRC)   // 36864
#define CHK 32
#define LNEPS 1e-5f

// ---------------- reduction helpers ----------------
__device__ __forceinline__ float wred_sum(float v){
#pragma unroll
  for(int o=32;o>=1;o>>=1) v += __shfl_xor(v,o,64);
  return v;
}
__device__ __forceinline__ float bred_sum(float v, float* s){
  v = wred_sum(v);
  int lane = threadIdx.x & 63, wid = threadIdx.x >> 6;
  if(lane==0) s[wid]=v;
  __syncthreads();
  float r = s[0]+s[1]+s[2]+s[3];
  __syncthreads();
  return r;
}
__device__ __forceinline__ float bred_max(float v, float* s){
#pragma unroll
  for(int o=32;o>=1;o>>=1) v = fmaxf(v, __shfl_xor(v,o,64));
  int lane = threadIdx.x & 63, wid = threadIdx.x >> 6;
  if(lane==0) s[wid]=v;
  __syncthreads();
  float r = fmaxf(fmaxf(s[0],s[1]),fmaxf(s[2],s[3]));
  __syncthreads();
  return r;
}

// ---------------- gating front-end ----------------
// partial column sums of aps/dvs per batch (deterministic two-stage)
__global__ void colsum_partial(const float* __restrict__ aps, const float* __restrict__ dvs,
                               float* __restrict__ pA, float* __restrict__ pD){
  int blk = blockIdx.x; int b = blk / CHK; int c = blk % CHK;
  int d = threadIdx.x;
  const int rows = NSRC / CHK;   // 288
  float sa=0.f, sd=0.f;
  size_t base = (size_t)b*NSRC*D + (size_t)(c*rows)*D + d;
  for(int r=0;r<rows;++r){
    sa += aps[base + (size_t)r*D];
    sd += dvs[base + (size_t)r*D];
  }
  pA[(b*CHK+c)*D + d] = sa;
  pD[(b*CHK+c)*D + d] = sd;
}

// s = colsum@W2 + N*b2 ; t = W1 @ s ; c = b1 . s   (per batch, per modality)
__global__ void gate_prep(const float* __restrict__ pA, const float* __restrict__ pD,
                          const float* __restrict__ w1a, const float* __restrict__ b1a,
                          const float* __restrict__ w2a, const float* __restrict__ b2a,
                          const float* __restrict__ w1d, const float* __restrict__ b1d,
                          const float* __restrict__ w2d, const float* __restrict__ b2d,
                          float* __restrict__ tA, float* __restrict__ tD, float* __restrict__ cAB){
  __shared__ float sumA[D], sumD[D], s2A[D], s2D[D], red[4];
  int b = blockIdx.x, t = threadIdx.x;
  float sa=0.f, sd=0.f;
  for(int c=0;c<CHK;++c){ sa += pA[(b*CHK+c)*D+t]; sd += pD[(b*CHK+c)*D+t]; }
  sumA[t]=sa; sumD[t]=sd;
  __syncthreads();
  float va=0.f, vd=0.f;
  for(int i=0;i<D;++i){ va += sumA[i]*w2a[i*D+t]; vd += sumD[i]*w2d[i*D+t]; }
  s2A[t] = va + (float)NSRC * b2a[t];
  s2D[t] = vd + (float)NSRC * b2d[t];
  __syncthreads();
  float ta=0.f, td=0.f;
  for(int j=0;j<D;++j){ ta += w1a[t*D+j]*s2A[j]; td += w1d[t*D+j]*s2D[j]; }
  tA[b*D+t]=ta; tD[b*D+t]=td;
  float ca = bred_sum(b1a[t]*s2A[t], red);
  float cd = bred_sum(b1d[t]*s2D[t], red);
  if(t==0){ cAB[b]=ca; cAB[BSZ+b]=cd; }
}

// per-row gate softmax + fused src
__global__ void gate_src(const float* __restrict__ aps, const float* __restrict__ dvs,
                         const float* __restrict__ tA, const float* __restrict__ tD,
                         const float* __restrict__ cAB, float* __restrict__ src){
  int w = threadIdx.x >> 6, lane = threadIdx.x & 63;
  size_t row = (size_t)blockIdx.x*4 + w;
  int b = (int)(row / NSRC);
  const float4* ap = (const float4*)(aps + row*D);
  const float4* dp = (const float4*)(dvs + row*D);
  const float4* tap = (const float4*)(tA + (size_t)b*D);
  const float4* tdp = (const float4*)(tD + (size_t)b*D);
  float4 a = ap[lane], dd = dp[lane], ta = tap[lane], td = tdp[lane];
  float ga = a.x*ta.x + a.y*ta.y + a.z*ta.z + a.w*ta.w;
  float gd = dd.x*td.x + dd.y*td.y + dd.z*td.z + dd.w*td.w;
  ga = (wred_sum(ga) + cAB[b]) * 0.0625f;       // 1/sqrt(256)
  gd = (wred_sum(gd) + cAB[BSZ+b]) * 0.0625f;
  float m = fmaxf(ga,gd);
  float ea = expf(ga-m), ed = expf(gd-m);
  float inv = 1.f/(ea+ed);
  float wa = ea*inv, wd = ed*inv;
  float4 o;
  o.x = wa*a.x + wd*dd.x; o.y = wa*a.y + wd*dd.y;
  o.z = wa*a.z + wd*dd.z; o.w = wa*a.w + wd*dd.w;
  ((float4*)(src + row*D))[lane] = o;
}

// init decoder target + reference points (ref identical across batch)
__global__ void init_out_ref(const float* __restrict__ qe, const float* __restrict__ refw,
                             const float* __restrict__ refb,
                             float* __restrict__ outb, float* __restrict__ refp,
                             float* __restrict__ dout){
  __shared__ float red[4];
  int q = blockIdx.x, t = threadIdx.x;
  float pos = qe[(size_t)q*2*D + t];
  float tgt = qe[(size_t)q*2*D + D + t];
  for(int b=0;b<BSZ;++b) outb[((size_t)b*NQ+q)*D + t] = tgt;
  float d0 = bred_sum(pos*refw[t*2+0], red);
  float d1 = bred_sum(pos*refw[t*2+1], red);
  if(t<2){
    float dot = (t==0? d0 : d1) + refb[t];
    float r = 1.f/(1.f+expf(-dot));
    refp[q*2+t] = r;
    const size_t o1 = (size_t)BSZ*NQ*D;
    const size_t o2 = o1 + (size_t)BSZ*NQ*2;
    for(int b=0;b<BSZ;++b){
      dout[o1 + (b*NQ+q)*2 + t] = r;
      dout[o2 + (b*NQ+q)*2 + t] = r;
    }
  }
}

// ---------------- tiled fp32 GEMM ----------------
// C[M,N] = (A [+ qpos]) @ W(ldw) + bias ; optional relu; optional row mask -> 0
__global__ void gemm64(const float* __restrict__ A, const float* __restrict__ qpos,
                       const float* __restrict__ W, const float* __restrict__ bias,
                       const unsigned char* __restrict__ rowmask,
                       float* __restrict__ C, int M, int K, int N, int ldw, int relu){
  __shared__ float As[16][64];
  __shared__ float Bs[16][64];
  int n0 = blockIdx.x*64, m0 = blockIdx.y*64;
  int t = threadIdx.x;
  int tm = (t>>4)<<2, tn = (t&15)<<2;
  int la_m = t>>2;            // (t*4)/16
  int la_k = (t&3)<<2;        // (t*4)%16
  int lb_k = t>>4;            // (t*4)/64
  int lb_n = (t&15)<<2;       // (t*4)%64
  float acc[4][4] = {};
  for(int k0=0;k0<K;k0+=16){
    int row = m0 + la_m;
    float4 av = make_float4(0.f,0.f,0.f,0.f);
    if(row < M){
      av = *(const float4*)(A + (size_t)row*K + k0 + la_k);
      if(qpos){
        float4 qv = *(const float4*)(qpos + (size_t)(row%NQ)*2*D + k0 + la_k);
        av.x+=qv.x; av.y+=qv.y; av.z+=qv.z; av.w+=qv.w;
      }
    }
    As[la_k+0][la_m]=av.x; As[la_k+1][la_m]=av.y;
    As[la_k+2][la_m]=av.z; As[la_k+3][la_m]=av.w;
    float4 wv = *(const float4*)(W + (size_t)(k0+lb_k)*ldw + n0 + lb_n);
    *(float4*)&Bs[lb_k][lb_n] = wv;
    __syncthreads();
#pragma unroll
    for(int k=0;k<16;++k){
      float4 a = *(float4*)&As[k][tm];
      float4 w4 = *(float4*)&Bs[k][tn];
      acc[0][0]+=a.x*w4.x; acc[0][1]+=a.x*w4.y; acc[0][2]+=a.x*w4.z; acc[0][3]+=a.x*w4.w;
      acc[1][0]+=a.y*w4.x; acc[1][1]+=a.y*w4.y; acc[1][2]+=a.y*w4.z; acc[1][3]+=a.y*w4.w;
      acc[2][0]+=a.z*w4.x; acc[2][1]+=a.z*w4.y; acc[2][2]+=a.z*w4.z; acc[2][3]+=a.z*w4.w;
      acc[3][0]+=a.w*w4.x; acc[3][1]+=a.w*w4.y; acc[3][2]+=a.w*w4.z; acc[3][3]+=a.w*w4.w;
    }
    __syncthreads();
  }
#pragma unroll
  for(int i=0;i<4;++i){
    int row = m0+tm+i;
    if(row >= M) continue;
    bool mz = rowmask && rowmask[row];
#pragma unroll
    for(int j=0;j<4;++j){
      int col = n0+tn+j;
      float v = acc[i][j] + (bias? bias[col] : 0.f);
      if(relu) v = fmaxf(v,0.f);
      if(mz) v = 0.f;
      C[(size_t)row*N + col] = v;
    }
  }
}

// small-N GEMM (N<=64): one block per row
__global__ void gemm_smallN(const float* __restrict__ A, const float* __restrict__ qpos,
                            const float* __restrict__ W, const float* __restrict__ bias,
                            float* __restrict__ C, int K, int N){
  int row = blockIdx.x; int n = threadIdx.x;
  if(n >= N) return;
  const float* ar = A + (size_t)row*K;
  const float* qr = qpos ? qpos + (size_t)(row%NQ)*2*D : nullptr;
  float acc = 0.f;
  for(int k=0;k<K;++k){
    float a = ar[k];
    if(qr) a += qr[k];
    acc += a * W[(size_t)k*N + n];
  }
  C[(size_t)row*N + n] = acc + bias[n];
}

// ---------------- self attention (per b,h,q) ----------------
__global__ void self_attn(const float* __restrict__ qh, const float* __restrict__ kh,
                          const float* __restrict__ vh, float* __restrict__ sa){
  __shared__ float qrow[HDIM];
  __shared__ float sc[NQ];
  __shared__ float part[8][HDIM];
  __shared__ float red[4];
  int blk = blockIdx.x;
  int q = blk % NQ; int bh = blk / NQ; int h = bh % NHD; int b = bh / NHD;
  int t = threadIdx.x;
  size_t qbase = ((size_t)(b*NQ+q))*D + h*HDIM;
  if(t < HDIM) qrow[t] = qh[qbase + t];
  __syncthreads();
  const float scale = 0.17677669529663687f;  // 1/sqrt(32)
  float lmax = -1e30f;
  for(int k=t;k<NQ;k+=256){
    const float4* kr = (const float4*)(kh + ((size_t)(b*NQ+k))*D + h*HDIM);
    float dot = 0.f;
#pragma unroll
    for(int i=0;i<8;++i){
      float4 kv = kr[i];
      float4 qv = *(float4*)&qrow[i*4];
      dot += kv.x*qv.x + kv.y*qv.y + kv.z*qv.z + kv.w*qv.w;
    }
    dot *= scale;
    sc[k] = dot;
    lmax = fmaxf(lmax, dot);
  }
  float bmax = bred_max(lmax, red);
  float lsum = 0.f;
  for(int k=t;k<NQ;k+=256){ float e = expf(sc[k]-bmax); sc[k]=e; lsum+=e; }
  float bsum = bred_sum(lsum, red);
  float inv = 1.f/bsum;
  __syncthreads();
  int g = t>>5, hd = t&31;
  float acc = 0.f;
  for(int k=g;k<NQ;k+=8) acc += sc[k]*vh[((size_t)(b*NQ+k))*D + h*HDIM + hd];
  part[g][hd] = acc;
  __syncthreads();
  if(g==0){
    float s = 0.f;
#pragma unroll
    for(int i=0;i<8;++i) s += part[i][hd];
    sa[qbase + hd] = s*inv;
  }
}

// ---------------- residual + layernorm ----------------
__global__ void residual_ln(const float* __restrict__ base, const float* __restrict__ delta,
                            const float* __restrict__ w, const float* __restrict__ bvec,
                            float* __restrict__ dst){
  __shared__ float red[4];
  size_t row = blockIdx.x; int t = threadIdx.x;
  float v = base[row*D+t] + delta[row*D+t];
  float mean = bred_sum(v, red) * (1.f/D);
  float c = v - mean;
  float var = bred_sum(c*c, red) * (1.f/D);
  dst[row*D+t] = c * rsqrtf(var + LNEPS) * w[t] + bvec[t];
}

// ---------------- deformable sampling ----------------
__global__ void deform_sample(const float* __restrict__ value, const float* __restrict__ offs,
                              const float* __restrict__ awl, const float* __restrict__ refp,
                              const float* __restrict__ vr, const int* __restrict__ sshape,
                              float* __restrict__ ca){
  int row = blockIdx.x; int b = row / NQ; int q = row % NQ;
  int t = threadIdx.x; int h = t>>5, hd = t&31;
  float Hf = (float)sshape[0], Wf = (float)sshape[1];
  int Ws = sshape[1];
  float rx = refp[q*2+0] * vr[b*2+0];
  float ry = refp[q*2+1] * vr[b*2+1];
  const float* lg = awl + (size_t)row*32 + h*4;
  float m = fmaxf(fmaxf(lg[0],lg[1]),fmaxf(lg[2],lg[3]));
  float e[4]; float esum=0.f;
#pragma unroll
  for(int p=0;p<4;++p){ e[p]=expf(lg[p]-m); esum+=e[p]; }
  float einv = 1.f/esum;
  const float* ofr = offs + (size_t)row*64 + h*8;
  const float* vbase = value + ((size_t)b*NSRC)*D + h*HDIM + hd;
  float acc = 0.f;
#pragma unroll
  for(int p=0;p<NPTS;++p){
    float lx = rx + ofr[p*2+0]/Wf;
    float ly = ry + ofr[p*2+1]/Hf;
    float x = lx*Wf - 0.5f, y = ly*Hf - 0.5f;
    float x0 = floorf(x), y0 = floorf(y);
    float wx = x-x0, wy = y-y0;
    float sample = 0.f;
#pragma unroll
    for(int cy=0;cy<2;++cy){
#pragma unroll
      for(int cx=0;cx<2;++cx){
        float xi = x0+cx, yi = y0+cy;
        float wgt = (cx? wx : 1.f-wx) * (cy? wy : 1.f-wy);
        bool valid = (xi>=0.f)&&(xi<=Wf-1.f)&&(yi>=0.f)&&(yi<=Hf-1.f);
        if(valid){
          int idx = (int)fminf(fmaxf(yi,0.f),Hf-1.f)*Ws + (int)fminf(fmaxf(xi,0.f),Wf-1.f);
          sample += wgt * vbase[(size_t)idx*D];
        }
      }
    }
    acc += (e[p]*einv) * sample;
  }
  ca[(size_t)row*D + h*HDIM + hd] = acc;
}

// ---------------- host ----------------
extern "C" void kernel_launch(void* const* d_in, const int* in_sizes, int n_in,
                              void* d_out, int out_size, void* d_ws, size_t ws_size,
                              hipStream_t stream){
  const float* aps=(const float*)d_in[0];
  const float* dvs=(const float*)d_in[1];
  const float* qe =(const float*)d_in[2];
  const float* vr =(const float*)d_in[3];
  const float* aps_w1=(const float*)d_in[4]; const float* aps_b1=(const float*)d_in[5];
  const float* aps_w2=(const float*)d_in[6]; const float* aps_b2=(const float*)d_in[7];
  const float* dvs_w1=(const float*)d_in[8]; const float* dvs_b1=(const float*)d_in[9];
  const float* dvs_w2=(const float*)d_in[10]; const float* dvs_b2=(const float*)d_in[11];
  const float* ref_w=(const float*)d_in[12]; const float* ref_b=(const float*)d_in[13];
  const float* saqkvw=(const float*)d_in[14]; const float* saqkvb=(const float*)d_in[15];
  const float* saoutw=(const float*)d_in[16]; const float* saoutb=(const float*)d_in[17];
  const float* offw=(const float*)d_in[18]; const float* offb=(const float*)d_in[19];
  const float* attnw=(const float*)d_in[20]; const float* attnb=(const float*)d_in[21];
  const float* valw=(const float*)d_in[22]; const float* valb=(const float*)d_in[23];
  const float* coutw=(const float*)d_in[24]; const float* coutb=(const float*)d_in[25];
  const float* ln1w=(const float*)d_in[26]; const float* ln1b=(const float*)d_in[27];
  const float* ln2w=(const float*)d_in[28]; const float* ln2b=(const float*)d_in[29];
  const float* ln3w=(const float*)d_in[30]; const float* ln3b=(const float*)d_in[31];
  const float* ffw1=(const float*)d_in[32]; const float* ffb1=(const float*)d_in[33];
  const float* ffw2=(const float*)d_in[34]; const float* ffb2=(const float*)d_in[35];
  const unsigned char* mask=(const unsigned char*)d_in[36];
  const int* sshape=(const int*)d_in[37];
  float* out = (float*)d_out;

  float* w = (float*)d_ws;
  size_t o = 0;
  float* src   = w+o; o += (size_t)NVROWS*D;
  float* value = w+o; o += (size_t)NVROWS*D;
  float* pA    = w+o; o += BSZ*CHK*D;
  float* pD    = w+o; o += BSZ*CHK*D;
  float* tA    = w+o; o += BSZ*D;
  float* tD    = w+o; o += BSZ*D;
  float* cAB   = w+o; o += 16;
  float* refp  = w+o; o += NQ*2;
  float* outb  = w+o; o += NROWS*D;
  float* qh    = w+o; o += NROWS*D;
  float* kh    = w+o; o += NROWS*D;
  float* vh    = w+o; o += NROWS*D;
  float* tmpa  = w+o; o += NROWS*D;
  float* tmpb  = w+o; o += NROWS*D;
  float* offsb = w+o; o += NROWS*64;
  float* awb   = w+o; o += NROWS*32;
  float* ffh   = w+o; o += (size_t)NROWS*FFD;

  colsum_partial<<<BSZ*CHK,256,0,stream>>>(aps,dvs,pA,pD);
  gate_prep<<<BSZ,256,0,stream>>>(pA,pD,aps_w1,aps_b1,aps_w2,aps_b2,
                                  dvs_w1,dvs_b1,dvs_w2,dvs_b2,tA,tD,cAB);
  gate_src<<<NVROWS/4,256,0,stream>>>(aps,dvs,tA,tD,cAB,src);
  init_out_ref<<<NQ,256,0,stream>>>(qe,ref_w,ref_b,outb,refp,out);

  dim3 g19(4,(NROWS+63)/64);          // N=256, M=1200
  dim3 gv(4,NVROWS/64);               // value GEMM
  dim3 gf1(FFD/64,(NROWS+63)/64);     // FFN up

  for(int l=0;l<NLAY;++l){
    const float* Wqkv = saqkvw + (size_t)l*D*3*D;
    const float* bqkv = saqkvb + (size_t)l*3*D;
    // qh, kh (input out+qpos), vh (input out)
    gemm64<<<g19,256,0,stream>>>(outb,qe,Wqkv,       bqkv,       nullptr,qh,NROWS,D,D,3*D,0);
    gemm64<<<g19,256,0,stream>>>(outb,qe,Wqkv+D,     bqkv+D,     nullptr,kh,NROWS,D,D,3*D,0);
    gemm64<<<g19,256,0,stream>>>(outb,nullptr,Wqkv+2*D,bqkv+2*D, nullptr,vh,NROWS,D,D,3*D,0);
    self_attn<<<BSZ*NHD*NQ,256,0,stream>>>(qh,kh,vh,tmpa);
    gemm64<<<g19,256,0,stream>>>(tmpa,nullptr,saoutw+(size_t)l*D*D,saoutb+(size_t)l*D,nullptr,tmpb,NROWS,D,D,D,0);
    residual_ln<<<NROWS,256,0,stream>>>(outb,tmpb,ln2w+(size_t)l*D,ln2b+(size_t)l*D,outb);

    // cross attention
    gemm64<<<gv,256,0,stream>>>(src,nullptr,valw+(size_t)l*D*D,valb+(size_t)l*D,mask,value,NVROWS,D,D,D,0);
    gemm_smallN<<<NROWS,64,0,stream>>>(outb,qe,offw+(size_t)l*D*64,offb+(size_t)l*64,offsb,D,64);
    gemm_smallN<<<NROWS,64,0,stream>>>(outb,qe,attnw+(size_t)l*D*32,attnb+(size_t)l*32,awb,D,32);
    deform_sample<<<NROWS,256,0,stream>>>(value,offsb,awb,refp,vr,sshape,tmpa);
    gemm64<<<g19,256,0,stream>>>(tmpa,nullptr,coutw+(size_t)l*D*D,coutb+(size_t)l*D,nullptr,tmpb,NROWS,D,D,D,0);
    residual_ln<<<NROWS,256,0,stream>>>(outb,tmpb,ln1w+(size_t)l*D,ln1b+(size_t)l*D,outb);

    // FFN
    gemm64<<<gf1,256,0,stream>>>(outb,nullptr,ffw1+(size_t)l*D*FFD,ffb1+(size_t)l*FFD,nullptr,ffh,NROWS,D,FFD,FFD,1);
    gemm64<<<g19,256,0,stream>>>(ffh,nullptr,ffw2+(size_t)l*FFD*D,ffb2+(size_t)l*D,nullptr,tmpb,NROWS,FFD,D,D,0);
    residual_ln<<<NROWS,256,0,stream>>>(outb,tmpb,ln3w+(size_t)l*D,ln3b+(size_t)l*D,
                                        (l==NLAY-1)? out : outb);
  }
}

// Round 2
// 2385.210 us; speedup vs baseline: 1.3444x; 1.3444x over previous
//
#include <hip/hip_runtime.h>
#include <math.h>

#define D 256
#define NHD 8
#define HDIM 32
#define NPTS 4
#define NLAY 6
#define FFD 1024
#define BSZ 4
#define NSRC 9216
#define NQ 300
#define NROWS (BSZ*NQ)      // 1200
#define NVROWS (BSZ*NSRC)   // 36864
#define CHK 32
#define LNEPS 1e-5f

// ---------------- reduction helpers ----------------
__device__ __forceinline__ float wred_sum(float v){
#pragma unroll
  for(int o=32;o>=1;o>>=1) v += __shfl_xor(v,o,64);
  return v;
}
__device__ __forceinline__ float bred_sum(float v, float* s){
  v = wred_sum(v);
  int lane = threadIdx.x & 63, wid = threadIdx.x >> 6;
  if(lane==0) s[wid]=v;
  __syncthreads();
  float r = s[0]+s[1]+s[2]+s[3];
  __syncthreads();
  return r;
}
__device__ __forceinline__ float bred_max(float v, float* s){
#pragma unroll
  for(int o=32;o>=1;o>>=1) v = fmaxf(v, __shfl_xor(v,o,64));
  int lane = threadIdx.x & 63, wid = threadIdx.x >> 6;
  if(lane==0) s[wid]=v;
  __syncthreads();
  float r = fmaxf(fmaxf(s[0],s[1]),fmaxf(s[2],s[3]));
  __syncthreads();
  return r;
}

// ---------------- gating front-end ----------------
__global__ void colsum_partial(const float* __restrict__ aps, const float* __restrict__ dvs,
                               float* __restrict__ pA, float* __restrict__ pD){
  int blk = blockIdx.x; int b = blk / CHK; int c = blk % CHK;
  int d = threadIdx.x;
  const int rows = NSRC / CHK;   // 288
  float sa=0.f, sd=0.f;
  size_t base = (size_t)b*NSRC*D + (size_t)(c*rows)*D + d;
  for(int r=0;r<rows;++r){
    sa += aps[base + (size_t)r*D];
    sd += dvs[base + (size_t)r*D];
  }
  pA[(b*CHK+c)*D + d] = sa;
  pD[(b*CHK+c)*D + d] = sd;
}

__global__ void gate_prep(const float* __restrict__ pA, const float* __restrict__ pD,
                          const float* __restrict__ w1a, const float* __restrict__ b1a,
                          const float* __restrict__ w2a, const float* __restrict__ b2a,
                          const float* __restrict__ w1d, const float* __restrict__ b1d,
                          const float* __restrict__ w2d, const float* __restrict__ b2d,
                          float* __restrict__ tA, float* __restrict__ tD, float* __restrict__ cAB){
  __shared__ float sumA[D], sumD[D], s2A[D], s2D[D], red[4];
  int b = blockIdx.x, t = threadIdx.x;
  float sa=0.f, sd=0.f;
  for(int c=0;c<CHK;++c){ sa += pA[(b*CHK+c)*D+t]; sd += pD[(b*CHK+c)*D+t]; }
  sumA[t]=sa; sumD[t]=sd;
  __syncthreads();
  float va=0.f, vd=0.f;
  for(int i=0;i<D;++i){ va += sumA[i]*w2a[i*D+t]; vd += sumD[i]*w2d[i*D+t]; }
  s2A[t] = va + (float)NSRC * b2a[t];
  s2D[t] = vd + (float)NSRC * b2d[t];
  __syncthreads();
  float ta=0.f, td=0.f;
  for(int j=0;j<D;++j){ ta += w1a[t*D+j]*s2A[j]; td += w1d[t*D+j]*s2D[j]; }
  tA[b*D+t]=ta; tD[b*D+t]=td;
  float ca = bred_sum(b1a[t]*s2A[t], red);
  float cd = bred_sum(b1d[t]*s2D[t], red);
  if(t==0){ cAB[b]=ca; cAB[BSZ+b]=cd; }
}

__global__ void gate_src(const float* __restrict__ aps, const float* __restrict__ dvs,
                         const float* __restrict__ tA, const float* __restrict__ tD,
                         const float* __restrict__ cAB, float* __restrict__ src){
  int w = threadIdx.x >> 6, lane = threadIdx.x & 63;
  size_t row = (size_t)blockIdx.x*4 + w;
  int b = (int)(row / NSRC);
  const float4* ap = (const float4*)(aps + row*D);
  const float4* dp = (const float4*)(dvs + row*D);
  const float4* tap = (const float4*)(tA + (size_t)b*D);
  const float4* tdp = (const float4*)(tD + (size_t)b*D);
  float4 a = ap[lane], dd = dp[lane], ta = tap[lane], td = tdp[lane];
  float ga = a.x*ta.x + a.y*ta.y + a.z*ta.z + a.w*ta.w;
  float gd = dd.x*td.x + dd.y*td.y + dd.z*td.z + dd.w*td.w;
  ga = (wred_sum(ga) + cAB[b]) * 0.0625f;       // 1/sqrt(256)
  gd = (wred_sum(gd) + cAB[BSZ+b]) * 0.0625f;
  float m = fmaxf(ga,gd);
  float ea = expf(ga-m), ed = expf(gd-m);
  float inv = 1.f/(ea+ed);
  float wa = ea*inv, wd = ed*inv;
  float4 o;
  o.x = wa*a.x + wd*dd.x; o.y = wa*a.y + wd*dd.y;
  o.z = wa*a.z + wd*dd.z; o.w = wa*a.w + wd*dd.w;
  ((float4*)(src + row*D))[lane] = o;
}

__global__ void init_out_ref(const float* __restrict__ qe, const float* __restrict__ refw,
                             const float* __restrict__ refb,
                             float* __restrict__ outb, float* __restrict__ refp,
                             float* __restrict__ dout){
  __shared__ float red[4];
  int q = blockIdx.x, t = threadIdx.x;
  float pos = qe[(size_t)q*2*D + t];
  float tgt = qe[(size_t)q*2*D + D + t];
  for(int b=0;b<BSZ;++b) outb[((size_t)b*NQ+q)*D + t] = tgt;
  float d0 = bred_sum(pos*refw[t*2+0], red);
  float d1 = bred_sum(pos*refw[t*2+1], red);
  if(t<2){
    float dot = (t==0? d0 : d1) + refb[t];
    float r = 1.f/(1.f+expf(-dot));
    refp[q*2+t] = r;
    const size_t o1 = (size_t)BSZ*NQ*D;
    const size_t o2 = o1 + (size_t)BSZ*NQ*2;
    for(int b=0;b<BSZ;++b){
      dout[o1 + (b*NQ+q)*2 + t] = r;
      dout[o2 + (b*NQ+q)*2 + t] = r;
    }
  }
}

// ---------------- tiled fp32 GEMM ----------------
__global__ void gemm64(const float* __restrict__ A, const float* __restrict__ qpos,
                       const float* __restrict__ W, const float* __restrict__ bias,
                       const unsigned char* __restrict__ rowmask,
                       float* __restrict__ C, int M, int K, int N, int ldw, int relu){
  __shared__ float As[16][64];
  __shared__ float Bs[16][64];
  int n0 = blockIdx.x*64, m0 = blockIdx.y*64;
  int t = threadIdx.x;
  int tm = (t>>4)<<2, tn = (t&15)<<2;
  int la_m = t>>2;
  int la_k = (t&3)<<2;
  int lb_k = t>>4;
  int lb_n = (t&15)<<2;
  float acc[4][4] = {};
  for(int k0=0;k0<K;k0+=16){
    int row = m0 + la_m;
    float4 av = make_float4(0.f,0.f,0.f,0.f);
    if(row < M){
      av = *(const float4*)(A + (size_t)row*K + k0 + la_k);
      if(qpos){
        float4 qv = *(const float4*)(qpos + (size_t)(row%NQ)*2*D + k0 + la_k);
        av.x+=qv.x; av.y+=qv.y; av.z+=qv.z; av.w+=qv.w;
      }
    }
    As[la_k+0][la_m]=av.x; As[la_k+1][la_m]=av.y;
    As[la_k+2][la_m]=av.z; As[la_k+3][la_m]=av.w;
    float4 wv = *(const float4*)(W + (size_t)(k0+lb_k)*ldw + n0 + lb_n);
    *(float4*)&Bs[lb_k][lb_n] = wv;
    __syncthreads();
#pragma unroll
    for(int k=0;k<16;++k){
      float4 a = *(float4*)&As[k][tm];
      float4 w4 = *(float4*)&Bs[k][tn];
      acc[0][0]+=a.x*w4.x; acc[0][1]+=a.x*w4.y; acc[0][2]+=a.x*w4.z; acc[0][3]+=a.x*w4.w;
      acc[1][0]+=a.y*w4.x; acc[1][1]+=a.y*w4.y; acc[1][2]+=a.y*w4.z; acc[1][3]+=a.y*w4.w;
      acc[2][0]+=a.z*w4.x; acc[2][1]+=a.z*w4.y; acc[2][2]+=a.z*w4.z; acc[2][3]+=a.z*w4.w;
      acc[3][0]+=a.w*w4.x; acc[3][1]+=a.w*w4.y; acc[3][2]+=a.w*w4.z; acc[3][3]+=a.w*w4.w;
    }
    __syncthreads();
  }
#pragma unroll
  for(int i=0;i<4;++i){
    int row = m0+tm+i;
    if(row >= M) continue;
    bool mz = rowmask && rowmask[row];
#pragma unroll
    for(int j=0;j<4;++j){
      int col = n0+tn+j;
      float v = acc[i][j] + (bias? bias[col] : 0.f);
      if(relu) v = fmaxf(v,0.f);
      if(mz) v = 0.f;
      C[(size_t)row*N + col] = v;
    }
  }
}

// ---------------- self attention (per b,h,q) ----------------
__global__ void self_attn(const float* __restrict__ qh, const float* __restrict__ kh,
                          const float* __restrict__ vh, float* __restrict__ sa){
  __shared__ float qrow[HDIM];
  __shared__ float sc[NQ];
  __shared__ float part[8][HDIM];
  __shared__ float red[4];
  int blk = blockIdx.x;
  int q = blk % NQ; int bh = blk / NQ; int h = bh % NHD; int b = bh / NHD;
  int t = threadIdx.x;
  size_t qbase = ((size_t)(b*NQ+q))*D + h*HDIM;
  if(t < HDIM) qrow[t] = qh[qbase + t];
  __syncthreads();
  const float scale = 0.17677669529663687f;  // 1/sqrt(32)
  float lmax = -1e30f;
  for(int k=t;k<NQ;k+=256){
    const float4* kr = (const float4*)(kh + ((size_t)(b*NQ+k))*D + h*HDIM);
    float dot = 0.f;
#pragma unroll
    for(int i=0;i<8;++i){
      float4 kv = kr[i];
      float4 qv = *(float4*)&qrow[i*4];
      dot += kv.x*qv.x + kv.y*qv.y + kv.z*qv.z + kv.w*qv.w;
    }
    dot *= scale;
    sc[k] = dot;
    lmax = fmaxf(lmax, dot);
  }
  float bmax = bred_max(lmax, red);
  float lsum = 0.f;
  for(int k=t;k<NQ;k+=256){ float e = expf(sc[k]-bmax); sc[k]=e; lsum+=e; }
  float bsum = bred_sum(lsum, red);
  float inv = 1.f/bsum;
  __syncthreads();
  int g = t>>5, hd = t&31;
  float acc = 0.f;
  for(int k=g;k<NQ;k+=8) acc += sc[k]*vh[((size_t)(b*NQ+k))*D + h*HDIM + hd];
  part[g][hd] = acc;
  __syncthreads();
  if(g==0){
    float s = 0.f;
#pragma unroll
    for(int i=0;i<8;++i) s += part[i][hd];
    sa[qbase + hd] = s*inv;
  }
}

// ---------------- residual + layernorm ----------------
__global__ void residual_ln(const float* __restrict__ base, const float* __restrict__ delta,
                            const float* __restrict__ w, const float* __restrict__ bvec,
                            float* __restrict__ dst){
  __shared__ float red[4];
  size_t row = blockIdx.x; int t = threadIdx.x;
  float v = base[row*D+t] + delta[row*D+t];
  float mean = bred_sum(v, red) * (1.f/D);
  float c = v - mean;
  float var = bred_sum(c*c, red) * (1.f/D);
  dst[row*D+t] = c * rsqrtf(var + LNEPS) * w[t] + bvec[t];
}

// ---------------- fused deformable cross-attn: proj + softmax + sampling ----
// one block (256 thr) per (b,q) row
__global__ void deform_attn(const float* __restrict__ outb, const float* __restrict__ qe,
                            const float* __restrict__ offw, const float* __restrict__ offb,
                            const float* __restrict__ attnw, const float* __restrict__ attnb,
                            const float* __restrict__ value, const float* __restrict__ refp,
                            const float* __restrict__ vr, const int* __restrict__ sshape,
                            float* __restrict__ ca){
  __shared__ float qrow[D];
  __shared__ float part[96][2];
  __shared__ float proj[96];
  int row = blockIdx.x; int b = row / NQ; int q = row % NQ;
  int t = threadIdx.x;
  qrow[t] = outb[(size_t)row*D + t] + qe[(size_t)q*2*D + t];
  __syncthreads();
  if(t < 192){
    int col = t >> 1, half = t & 1;
    float acc = 0.f;
    if(col < 64){
      const float* W = offw;
      for(int k=half*128; k<half*128+128; ++k) acc += qrow[k]*W[(size_t)k*64 + col];
    } else {
      const float* W = attnw; int c = col-64;
      for(int k=half*128; k<half*128+128; ++k) acc += qrow[k]*W[(size_t)k*32 + c];
    }
    part[col][half] = acc;
  }
  __syncthreads();
  if(t < 96) proj[t] = part[t][0] + part[t][1] + (t<64 ? offb[t] : attnb[t-64]);
  __syncthreads();

  int h = t>>5, hd = t&31;
  float Hf = (float)sshape[0], Wf = (float)sshape[1];
  int Ws = sshape[1];
  float rx = refp[q*2+0] * vr[b*2+0];
  float ry = refp[q*2+1] * vr[b*2+1];
  const float* lg = &proj[64 + h*4];
  float m = fmaxf(fmaxf(lg[0],lg[1]),fmaxf(lg[2],lg[3]));
  float e[4]; float esum=0.f;
#pragma unroll
  for(int p=0;p<4;++p){ e[p]=expf(lg[p]-m); esum+=e[p]; }
  float einv = 1.f/esum;
  const float* ofr = &proj[h*8];
  const float* vbase = value + ((size_t)b*NSRC)*D + h*HDIM + hd;
  float acc = 0.f;
#pragma unroll
  for(int p=0;p<NPTS;++p){
    float lx = rx + ofr[p*2+0]/Wf;
    float ly = ry + ofr[p*2+1]/Hf;
    float x = lx*Wf - 0.5f, y = ly*Hf - 0.5f;
    float x0 = floorf(x), y0 = floorf(y);
    float wx = x-x0, wy = y-y0;
    float sample = 0.f;
#pragma unroll
    for(int cy=0;cy<2;++cy){
#pragma unroll
      for(int cx=0;cx<2;++cx){
        float xi = x0+cx, yi = y0+cy;
        float wgt = (cx? wx : 1.f-wx) * (cy? wy : 1.f-wy);
        bool valid = (xi>=0.f)&&(xi<=Wf-1.f)&&(yi>=0.f)&&(yi<=Hf-1.f);
        if(valid){
          int idx = (int)fminf(fmaxf(yi,0.f),Hf-1.f)*Ws + (int)fminf(fmaxf(xi,0.f),Wf-1.f);
          sample += wgt * vbase[(size_t)idx*D];
        }
      }
    }
    acc += (e[p]*einv) * sample;
  }
  ca[(size_t)row*D + h*HDIM + hd] = acc;
}

// ---------------- host ----------------
extern "C" void kernel_launch(void* const* d_in, const int* in_sizes, int n_in,
                              void* d_out, int out_size, void* d_ws, size_t ws_size,
                              hipStream_t stream){
  const float* aps=(const float*)d_in[0];
  const float* dvs=(const float*)d_in[1];
  const float* qe =(const float*)d_in[2];
  const float* vr =(const float*)d_in[3];
  const float* aps_w1=(const float*)d_in[4]; const float* aps_b1=(const float*)d_in[5];
  const float* aps_w2=(const float*)d_in[6]; const float* aps_b2=(const float*)d_in[7];
  const float* dvs_w1=(const float*)d_in[8]; const float* dvs_b1=(const float*)d_in[9];
  const float* dvs_w2=(const float*)d_in[10]; const float* dvs_b2=(const float*)d_in[11];
  const float* ref_w=(const float*)d_in[12]; const float* ref_b=(const float*)d_in[13];
  const float* saqkvw=(const float*)d_in[14]; const float* saqkvb=(const float*)d_in[15];
  const float* saoutw=(const float*)d_in[16]; const float* saoutb=(const float*)d_in[17];
  const float* offw=(const float*)d_in[18]; const float* offb=(const float*)d_in[19];
  const float* attnw=(const float*)d_in[20]; const float* attnb=(const float*)d_in[21];
  const float* valw=(const float*)d_in[22]; const float* valb=(const float*)d_in[23];
  const float* coutw=(const float*)d_in[24]; const float* coutb=(const float*)d_in[25];
  const float* ln1w=(const float*)d_in[26]; const float* ln1b=(const float*)d_in[27];
  const float* ln2w=(const float*)d_in[28]; const float* ln2b=(const float*)d_in[29];
  const float* ln3w=(const float*)d_in[30]; const float* ln3b=(const float*)d_in[31];
  const float* ffw1=(const float*)d_in[32]; const float* ffb1=(const float*)d_in[33];
  const float* ffw2=(const float*)d_in[34]; const float* ffb2=(const float*)d_in[35];
  const unsigned char* mask=(const unsigned char*)d_in[36];
  const int* sshape=(const int*)d_in[37];
  float* out = (float*)d_out;

  float* w = (float*)d_ws;
  size_t o = 0;
  float* src   = w+o; o += (size_t)NVROWS*D;
  float* value = w+o; o += (size_t)NVROWS*D;
  float* pA    = w+o; o += BSZ*CHK*D;
  float* pD    = w+o; o += BSZ*CHK*D;
  float* tA    = w+o; o += BSZ*D;
  float* tD    = w+o; o += BSZ*D;
  float* cAB   = w+o; o += 16;
  float* refp  = w+o; o += NQ*2;
  float* outb  = w+o; o += NROWS*D;
  float* qh    = w+o; o += NROWS*D;
  float* kh    = w+o; o += NROWS*D;
  float* vh    = w+o; o += NROWS*D;
  float* tmpa  = w+o; o += NROWS*D;
  float* tmpb  = w+o; o += NROWS*D;
  float* ffh   = w+o; o += (size_t)NROWS*FFD;

  colsum_partial<<<BSZ*CHK,256,0,stream>>>(aps,dvs,pA,pD);
  gate_prep<<<BSZ,256,0,stream>>>(pA,pD,aps_w1,aps_b1,aps_w2,aps_b2,
                                  dvs_w1,dvs_b1,dvs_w2,dvs_b2,tA,tD,cAB);
  gate_src<<<NVROWS/4,256,0,stream>>>(aps,dvs,tA,tD,cAB,src);
  init_out_ref<<<NQ,256,0,stream>>>(qe,ref_w,ref_b,outb,refp,out);

  dim3 g19(4,(NROWS+63)/64);          // N=256, M=1200
  dim3 gv(4,NVROWS/64);               // value GEMM
  dim3 gf1(FFD/64,(NROWS+63)/64);     // FFN up

  for(int l=0;l<NLAY;++l){
    const float* Wqkv = saqkvw + (size_t)l*D*3*D;
    const float* bqkv = saqkvb + (size_t)l*3*D;
    gemm64<<<g19,256,0,stream>>>(outb,qe,Wqkv,       bqkv,       nullptr,qh,NROWS,D,D,3*D,0);
    gemm64<<<g19,256,0,stream>>>(outb,qe,Wqkv+D,     bqkv+D,     nullptr,kh,NROWS,D,D,3*D,0);
    gemm64<<<g19,256,0,stream>>>(outb,nullptr,Wqkv+2*D,bqkv+2*D, nullptr,vh,NROWS,D,D,3*D,0);
    self_attn<<<BSZ*NHD*NQ,256,0,stream>>>(qh,kh,vh,tmpa);
    gemm64<<<g19,256,0,stream>>>(tmpa,nullptr,saoutw+(size_t)l*D*D,saoutb+(size_t)l*D,nullptr,tmpb,NROWS,D,D,D,0);
    residual_ln<<<NROWS,256,0,stream>>>(outb,tmpb,ln2w+(size_t)l*D,ln2b+(size_t)l*D,outb);

    // cross attention
    gemm64<<<gv,256,0,stream>>>(src,nullptr,valw+(size_t)l*D*D,valb+(size_t)l*D,mask,value,NVROWS,D,D,D,0);
    deform_attn<<<NROWS,256,0,stream>>>(outb,qe,
                                        offw+(size_t)l*D*64, offb+(size_t)l*64,
                                        attnw+(size_t)l*D*32, attnb+(size_t)l*32,
                                        value,refp,vr,sshape,tmpa);
    gemm64<<<g19,256,0,stream>>>(tmpa,nullptr,coutw+(size_t)l*D*D,coutb+(size_t)l*D,nullptr,tmpb,NROWS,D,D,D,0);
    residual_ln<<<NROWS,256,0,stream>>>(outb,tmpb,ln1w+(size_t)l*D,ln1b+(size_t)l*D,outb);

    // FFN
    gemm64<<<gf1,256,0,stream>>>(outb,nullptr,ffw1+(size_t)l*D*FFD,ffb1+(size_t)l*FFD,nullptr,ffh,NROWS,D,FFD,FFD,1);
    gemm64<<<g19,256,0,stream>>>(ffh,nullptr,ffw2+(size_t)l*FFD*D,ffb2+(size_t)l*D,nullptr,tmpb,NROWS,FFD,D,D,0);
    residual_ln<<<NROWS,256,0,stream>>>(outb,tmpb,ln3w+(size_t)l*D,ln3b+(size_t)l*D,
                                        (l==NLAY-1)? out : outb);
  }
}

// Round 3
// 1972.298 us; speedup vs baseline: 1.6259x; 1.2094x over previous
//
#include <hip/hip_runtime.h>
#include <math.h>

#define D 256
#define NHD 8
#define HDIM 32
#define NPTS 4
#define NLAY 6
#define FFD 1024
#define BSZ 4
#define NSRC 9216
#define NQ 300
#define NROWS (BSZ*NQ)      // 1200
#define NVROWS (BSZ*NSRC)   // 36864
#define CHK 32
#define LNEPS 1e-5f

typedef __attribute__((ext_vector_type(8))) short short8v;
typedef __attribute__((ext_vector_type(4))) float f32x4;

__device__ __forceinline__ unsigned short f2bf(float f){
  unsigned u = __float_as_uint(f);
  unsigned r = (u + 0x7FFFu + ((u>>16)&1u)) >> 16;
  return (unsigned short)r;
}

// ---------------- reduction helpers ----------------
__device__ __forceinline__ float wred_sum(float v){
#pragma unroll
  for(int o=32;o>=1;o>>=1) v += __shfl_xor(v,o,64);
  return v;
}
__device__ __forceinline__ float bred_sum(float v, float* s){
  v = wred_sum(v);
  int lane = threadIdx.x & 63, wid = threadIdx.x >> 6;
  if(lane==0) s[wid]=v;
  __syncthreads();
  float r = s[0]+s[1]+s[2]+s[3];
  __syncthreads();
  return r;
}

// ---------------- gating front-end ----------------
__global__ void colsum_partial(const float* __restrict__ aps, const float* __restrict__ dvs,
                               float* __restrict__ pA, float* __restrict__ pD){
  int blk = blockIdx.x; int b = blk / CHK; int c = blk % CHK;
  int d = threadIdx.x;
  const int rows = NSRC / CHK;   // 288
  float sa=0.f, sd=0.f;
  size_t base = (size_t)b*NSRC*D + (size_t)(c*rows)*D + d;
  for(int r=0;r<rows;++r){
    sa += aps[base + (size_t)r*D];
    sd += dvs[base + (size_t)r*D];
  }
  pA[(b*CHK+c)*D + d] = sa;
  pD[(b*CHK+c)*D + d] = sd;
}

__global__ void gate_prep(const float* __restrict__ pA, const float* __restrict__ pD,
                          const float* __restrict__ w1a, const float* __restrict__ b1a,
                          const float* __restrict__ w2a, const float* __restrict__ b2a,
                          const float* __restrict__ w1d, const float* __restrict__ b1d,
                          const float* __restrict__ w2d, const float* __restrict__ b2d,
                          float* __restrict__ tA, float* __restrict__ tD, float* __restrict__ cAB){
  __shared__ float sumA[D], sumD[D], s2A[D], s2D[D], red[4];
  int b = blockIdx.x, t = threadIdx.x;
  float sa=0.f, sd=0.f;
  for(int c=0;c<CHK;++c){ sa += pA[(b*CHK+c)*D+t]; sd += pD[(b*CHK+c)*D+t]; }
  sumA[t]=sa; sumD[t]=sd;
  __syncthreads();
  float va=0.f, vd=0.f;
  for(int i=0;i<D;++i){ va += sumA[i]*w2a[i*D+t]; vd += sumD[i]*w2d[i*D+t]; }
  s2A[t] = va + (float)NSRC * b2a[t];
  s2D[t] = vd + (float)NSRC * b2d[t];
  __syncthreads();
  float ta=0.f, td=0.f;
  for(int j=0;j<D;++j){ ta += w1a[t*D+j]*s2A[j]; td += w1d[t*D+j]*s2D[j]; }
  tA[b*D+t]=ta; tD[b*D+t]=td;
  float ca = bred_sum(b1a[t]*s2A[t], red);
  float cd = bred_sum(b1d[t]*s2D[t], red);
  if(t==0){ cAB[b]=ca; cAB[BSZ+b]=cd; }
}

// per-row gate softmax + fused src (emits bf16 for the MFMA value GEMM)
__global__ void gate_src(const float* __restrict__ aps, const float* __restrict__ dvs,
                         const float* __restrict__ tA, const float* __restrict__ tD,
                         const float* __restrict__ cAB, unsigned short* __restrict__ srcb){
  int w = threadIdx.x >> 6, lane = threadIdx.x & 63;
  size_t row = (size_t)blockIdx.x*4 + w;
  int b = (int)(row / NSRC);
  const float4* ap = (const float4*)(aps + row*D);
  const float4* dp = (const float4*)(dvs + row*D);
  const float4* tap = (const float4*)(tA + (size_t)b*D);
  const float4* tdp = (const float4*)(tD + (size_t)b*D);
  float4 a = ap[lane], dd = dp[lane], ta = tap[lane], td = tdp[lane];
  float ga = a.x*ta.x + a.y*ta.y + a.z*ta.z + a.w*ta.w;
  float gd = dd.x*td.x + dd.y*td.y + dd.z*td.z + dd.w*td.w;
  ga = (wred_sum(ga) + cAB[b]) * 0.0625f;       // 1/sqrt(256)
  gd = (wred_sum(gd) + cAB[BSZ+b]) * 0.0625f;
  float m = fmaxf(ga,gd);
  float ea = expf(ga-m), ed = expf(gd-m);
  float inv = 1.f/(ea+ed);
  float wa = ea*inv, wd = ed*inv;
  ushort4 o;
  o.x = f2bf(wa*a.x + wd*dd.x); o.y = f2bf(wa*a.y + wd*dd.y);
  o.z = f2bf(wa*a.z + wd*dd.z); o.w = f2bf(wa*a.w + wd*dd.w);
  ((ushort4*)(srcb + row*D))[lane] = o;
}

// convert+transpose val weights to bf16 [NLAY][N][K] once per call
__global__ void wconv(const float* __restrict__ W, unsigned short* __restrict__ Bt){
  __shared__ float tile[32][33];
  int blk = blockIdx.x; int l = blk/64; int rem = blk%64; int tk = rem/8, tn = rem%8;
  int tx = threadIdx.x & 31, ty = threadIdx.x >> 5;
  const float* Wl = W + (size_t)l*D*D;
  unsigned short* Btl = Bt + (size_t)l*D*D;
#pragma unroll
  for(int i=0;i<4;++i)
    tile[ty+i*8][tx] = Wl[(size_t)(tk*32+ty+i*8)*D + tn*32+tx];
  __syncthreads();
#pragma unroll
  for(int i=0;i<4;++i)
    Btl[(size_t)(tn*32+ty+i*8)*D + tk*32+tx] = f2bf(tile[tx][ty+i*8]);
}

__global__ void init_out_ref(const float* __restrict__ qe, const float* __restrict__ refw,
                             const float* __restrict__ refb,
                             float* __restrict__ outb, float* __restrict__ refp,
                             float* __restrict__ dout){
  __shared__ float red[4];
  int q = blockIdx.x, t = threadIdx.x;
  float pos = qe[(size_t)q*2*D + t];
  float tgt = qe[(size_t)q*2*D + D + t];
  for(int b=0;b<BSZ;++b) outb[((size_t)b*NQ+q)*D + t] = tgt;
  float d0 = bred_sum(pos*refw[t*2+0], red);
  float d1 = bred_sum(pos*refw[t*2+1], red);
  if(t<2){
    float dot = (t==0? d0 : d1) + refb[t];
    float r = 1.f/(1.f+expf(-dot));
    refp[q*2+t] = r;
    const size_t o1 = (size_t)BSZ*NQ*D;
    const size_t o2 = o1 + (size_t)BSZ*NQ*2;
    for(int b=0;b<BSZ;++b){
      dout[o1 + (b*NQ+q)*2 + t] = r;
      dout[o2 + (b*NQ+q)*2 + t] = r;
    }
  }
}

// ---------------- bf16 MFMA value GEMM: C[M,256] = A@W + bias, row-masked ----
__global__ __launch_bounds__(256) void mfma_value(
    const unsigned short* __restrict__ Abf,   // [M][256] bf16
    const unsigned short* __restrict__ Bt,    // [256][256] bf16, Bt[n][k]
    const float* __restrict__ bias, const unsigned char* __restrict__ rowmask,
    float* __restrict__ C){
  __shared__ unsigned short As[128][40];
  __shared__ unsigned short Bs[128][40];
  int m0 = blockIdx.x*128, n0 = blockIdx.y*128;
  int t = threadIdx.x;
  int wave = t>>6, lane = t&63;
  int wm = (wave>>1)*64, wn = (wave&1)*64;
  f32x4 acc[4][4];
#pragma unroll
  for(int i=0;i<4;++i)
#pragma unroll
    for(int j=0;j<4;++j)
#pragma unroll
      for(int r=0;r<4;++r) acc[i][j][r]=0.f;

  int r0 = t>>2, c0 = (t&3)*8;       // first chunk
  int r1 = (t+256)>>2;               // second chunk (same c0 pattern)
  for(int k0=0;k0<256;k0+=32){
    *(uint4*)&As[r0][c0] = *(const uint4*)(Abf + (size_t)(m0+r0)*256 + k0 + c0);
    *(uint4*)&As[r1][c0] = *(const uint4*)(Abf + (size_t)(m0+r1)*256 + k0 + c0);
    *(uint4*)&Bs[r0][c0] = *(const uint4*)(Bt  + (size_t)(n0+r0)*256 + k0 + c0);
    *(uint4*)&Bs[r1][c0] = *(const uint4*)(Bt  + (size_t)(n0+r1)*256 + k0 + c0);
    __syncthreads();
    short8v a[4], bb[4];
#pragma unroll
    for(int mf=0;mf<4;++mf) a[mf]  = *(short8v*)&As[wm+mf*16+(lane&15)][(lane>>4)*8];
#pragma unroll
    for(int nf=0;nf<4;++nf) bb[nf] = *(short8v*)&Bs[wn+nf*16+(lane&15)][(lane>>4)*8];
#pragma unroll
    for(int mf=0;mf<4;++mf)
#pragma unroll
      for(int nf=0;nf<4;++nf)
        acc[mf][nf] = __builtin_amdgcn_mfma_f32_16x16x32_bf16(a[mf], bb[nf], acc[mf][nf], 0,0,0);
    __syncthreads();
  }
  // D mapping: col = lane&15, row = (lane>>4)*4 + reg
#pragma unroll
  for(int mf=0;mf<4;++mf){
    int rbase = m0 + wm + mf*16 + (lane>>4)*4;
#pragma unroll
    for(int nf=0;nf<4;++nf){
      int col = n0 + wn + nf*16 + (lane&15);
      float bv = bias[col];
#pragma unroll
      for(int r=0;r<4;++r){
        int row = rbase + r;
        float v = acc[mf][nf][r] + bv;
        if(rowmask[row]) v = 0.f;
        C[(size_t)row*256 + col] = v;
      }
    }
  }
}

// ---------------- tiled fp32 GEMM (M=1200 chains) ----------------
__global__ void gemm64(const float* __restrict__ A, const float* __restrict__ qpos,
                       const float* __restrict__ W, const float* __restrict__ bias,
                       float* __restrict__ C, int M, int K, int N, int ldw, int relu){
  __shared__ float As[16][64];
  __shared__ float Bs[16][64];
  int n0 = blockIdx.x*64, m0 = blockIdx.y*64;
  int t = threadIdx.x;
  int tm = (t>>4)<<2, tn = (t&15)<<2;
  int la_m = t>>2;
  int la_k = (t&3)<<2;
  int lb_k = t>>4;
  int lb_n = (t&15)<<2;
  float acc[4][4] = {};
  for(int k0=0;k0<K;k0+=16){
    int row = m0 + la_m;
    float4 av = make_float4(0.f,0.f,0.f,0.f);
    if(row < M){
      av = *(const float4*)(A + (size_t)row*K + k0 + la_k);
      if(qpos){
        float4 qv = *(const float4*)(qpos + (size_t)(row%NQ)*2*D + k0 + la_k);
        av.x+=qv.x; av.y+=qv.y; av.z+=qv.z; av.w+=qv.w;
      }
    }
    As[la_k+0][la_m]=av.x; As[la_k+1][la_m]=av.y;
    As[la_k+2][la_m]=av.z; As[la_k+3][la_m]=av.w;
    float4 wv = *(const float4*)(W + (size_t)(k0+lb_k)*ldw + n0 + lb_n);
    *(float4*)&Bs[lb_k][lb_n] = wv;
    __syncthreads();
#pragma unroll
    for(int k=0;k<16;++k){
      float4 a = *(float4*)&As[k][tm];
      float4 w4 = *(float4*)&Bs[k][tn];
      acc[0][0]+=a.x*w4.x; acc[0][1]+=a.x*w4.y; acc[0][2]+=a.x*w4.z; acc[0][3]+=a.x*w4.w;
      acc[1][0]+=a.y*w4.x; acc[1][1]+=a.y*w4.y; acc[1][2]+=a.y*w4.z; acc[1][3]+=a.y*w4.w;
      acc[2][0]+=a.z*w4.x; acc[2][1]+=a.z*w4.y; acc[2][2]+=a.z*w4.z; acc[2][3]+=a.z*w4.w;
      acc[3][0]+=a.w*w4.x; acc[3][1]+=a.w*w4.y; acc[3][2]+=a.w*w4.z; acc[3][3]+=a.w*w4.w;
    }
    __syncthreads();
  }
#pragma unroll
  for(int i=0;i<4;++i){
    int row = m0+tm+i;
    if(row >= M) continue;
#pragma unroll
    for(int j=0;j<4;++j){
      int col = n0+tn+j;
      float v = acc[i][j] + (bias? bias[col] : 0.f);
      if(relu) v = fmaxf(v,0.f);
      C[(size_t)row*N + col] = v;
    }
  }
}

// ---------------- self attention: one WAVE per (b,h,q) ----------------
__global__ void self_attn(const float* __restrict__ qh, const float* __restrict__ kh,
                          const float* __restrict__ vh, float* __restrict__ sa){
  __shared__ float qs[4][32];
  __shared__ float scs[4][NQ];
  int w = threadIdx.x>>6, lane = threadIdx.x&63;
  int g = blockIdx.x*4 + w;
  int q = g % NQ; int bh = g/NQ; int h = bh % NHD; int b = bh/NHD;
  size_t qbase = ((size_t)(b*NQ+q))*D + h*HDIM;
  if(lane<32) qs[w][lane] = qh[qbase+lane];
  __syncthreads();
  const float scale = 0.17677669529663687f;  // 1/sqrt(32)
  float lmax = -1e30f;
  for(int k=lane;k<NQ;k+=64){
    const float4* kr = (const float4*)(kh + ((size_t)(b*NQ+k))*D + h*HDIM);
    float dot = 0.f;
#pragma unroll
    for(int i=0;i<8;++i){
      float4 kv = kr[i];
      float4 qv = *(float4*)&qs[w][i*4];
      dot += kv.x*qv.x + kv.y*qv.y + kv.z*qv.z + kv.w*qv.w;
    }
    dot *= scale;
    scs[w][k] = dot;
    lmax = fmaxf(lmax, dot);
  }
#pragma unroll
  for(int o=32;o>=1;o>>=1) lmax = fmaxf(lmax, __shfl_xor(lmax,o,64));
  float lsum = 0.f;
  for(int k=lane;k<NQ;k+=64){ float e = expf(scs[w][k]-lmax); scs[w][k]=e; lsum+=e; }
  lsum = wred_sum(lsum);
  float inv = 1.f/lsum;
  __syncthreads();
  int half = lane>>5, hd = lane&31;
  float acc = 0.f;
#pragma unroll 2
  for(int k=half;k<NQ;k+=2)
    acc += scs[w][k] * vh[((size_t)(b*NQ+k))*D + h*HDIM + hd];
  acc += __shfl_xor(acc,32,64);
  if(half==0) sa[qbase+hd] = acc*inv;
}

// ---------------- residual + layernorm ----------------
__global__ void residual_ln(const float* __restrict__ base, const float* __restrict__ delta,
                            const float* __restrict__ w, const float* __restrict__ bvec,
                            float* __restrict__ dst){
  __shared__ float red[4];
  size_t row = blockIdx.x; int t = threadIdx.x;
  float v = base[row*D+t] + delta[row*D+t];
  float mean = bred_sum(v, red) * (1.f/D);
  float c = v - mean;
  float var = bred_sum(c*c, red) * (1.f/D);
  dst[row*D+t] = c * rsqrtf(var + LNEPS) * w[t] + bvec[t];
}

// ---------------- fused deformable cross-attn ----------------
__global__ void deform_attn(const float* __restrict__ outb, const float* __restrict__ qe,
                            const float* __restrict__ offw, const float* __restrict__ offb,
                            const float* __restrict__ attnw, const float* __restrict__ attnb,
                            const float* __restrict__ value, const float* __restrict__ refp,
                            const float* __restrict__ vr, const int* __restrict__ sshape,
                            float* __restrict__ ca){
  __shared__ float qrow[D];
  __shared__ float part[96][2];
  __shared__ float proj[96];
  int row = blockIdx.x; int b = row / NQ; int q = row % NQ;
  int t = threadIdx.x;
  qrow[t] = outb[(size_t)row*D + t] + qe[(size_t)q*2*D + t];
  __syncthreads();
  if(t < 192){
    int col = t >> 1, half = t & 1;
    float acc = 0.f;
    if(col < 64){
      const float* W = offw;
      for(int k=half*128; k<half*128+128; ++k) acc += qrow[k]*W[(size_t)k*64 + col];
    } else {
      const float* W = attnw; int c = col-64;
      for(int k=half*128; k<half*128+128; ++k) acc += qrow[k]*W[(size_t)k*32 + c];
    }
    part[col][half] = acc;
  }
  __syncthreads();
  if(t < 96) proj[t] = part[t][0] + part[t][1] + (t<64 ? offb[t] : attnb[t-64]);
  __syncthreads();

  int h = t>>5, hd = t&31;
  float Hf = (float)sshape[0], Wf = (float)sshape[1];
  int Ws = sshape[1];
  float rx = refp[q*2+0] * vr[b*2+0];
  float ry = refp[q*2+1] * vr[b*2+1];
  const float* lg = &proj[64 + h*4];
  float m = fmaxf(fmaxf(lg[0],lg[1]),fmaxf(lg[2],lg[3]));
  float e[4]; float esum=0.f;
#pragma unroll
  for(int p=0;p<4;++p){ e[p]=expf(lg[p]-m); esum+=e[p]; }
  float einv = 1.f/esum;
  const float* ofr = &proj[h*8];
  const float* vbase = value + ((size_t)b*NSRC)*D + h*HDIM + hd;
  float acc = 0.f;
#pragma unroll
  for(int p=0;p<NPTS;++p){
    float lx = rx + ofr[p*2+0]/Wf;
    float ly = ry + ofr[p*2+1]/Hf;
    float x = lx*Wf - 0.5f, y = ly*Hf - 0.5f;
    float x0 = floorf(x), y0 = floorf(y);
    float wx = x-x0, wy = y-y0;
    float sample = 0.f;
#pragma unroll
    for(int cy=0;cy<2;++cy){
#pragma unroll
      for(int cx=0;cx<2;++cx){
        float xi = x0+cx, yi = y0+cy;
        float wgt = (cx? wx : 1.f-wx) * (cy? wy : 1.f-wy);
        bool valid = (xi>=0.f)&&(xi<=Wf-1.f)&&(yi>=0.f)&&(yi<=Hf-1.f);
        if(valid){
          int idx = (int)fminf(fmaxf(yi,0.f),Hf-1.f)*Ws + (int)fminf(fmaxf(xi,0.f),Wf-1.f);
          sample += wgt * vbase[(size_t)idx*D];
        }
      }
    }
    acc += (e[p]*einv) * sample;
  }
  ca[(size_t)row*D + h*HDIM + hd] = acc;
}

// ---------------- host ----------------
extern "C" void kernel_launch(void* const* d_in, const int* in_sizes, int n_in,
                              void* d_out, int out_size, void* d_ws, size_t ws_size,
                              hipStream_t stream){
  const float* aps=(const float*)d_in[0];
  const float* dvs=(const float*)d_in[1];
  const float* qe =(const float*)d_in[2];
  const float* vr =(const float*)d_in[3];
  const float* aps_w1=(const float*)d_in[4]; const float* aps_b1=(const float*)d_in[5];
  const float* aps_w2=(const float*)d_in[6]; const float* aps_b2=(const float*)d_in[7];
  const float* dvs_w1=(const float*)d_in[8]; const float* dvs_b1=(const float*)d_in[9];
  const float* dvs_w2=(const float*)d_in[10]; const float* dvs_b2=(const float*)d_in[11];
  const float* ref_w=(const float*)d_in[12]; const float* ref_b=(const float*)d_in[13];
  const float* saqkvw=(const float*)d_in[14]; const float* saqkvb=(const float*)d_in[15];
  const float* saoutw=(const float*)d_in[16]; const float* saoutb=(const float*)d_in[17];
  const float* offw=(const float*)d_in[18]; const float* offb=(const float*)d_in[19];
  const float* attnw=(const float*)d_in[20]; const float* attnb=(const float*)d_in[21];
  const float* valw=(const float*)d_in[22]; const float* valb=(const float*)d_in[23];
  const float* coutw=(const float*)d_in[24]; const float* coutb=(const float*)d_in[25];
  const float* ln1w=(const float*)d_in[26]; const float* ln1b=(const float*)d_in[27];
  const float* ln2w=(const float*)d_in[28]; const float* ln2b=(const float*)d_in[29];
  const float* ln3w=(const float*)d_in[30]; const float* ln3b=(const float*)d_in[31];
  const float* ffw1=(const float*)d_in[32]; const float* ffb1=(const float*)d_in[33];
  const float* ffw2=(const float*)d_in[34]; const float* ffb2=(const float*)d_in[35];
  const unsigned char* mask=(const unsigned char*)d_in[36];
  const int* sshape=(const int*)d_in[37];
  float* out = (float*)d_out;

  char* wsb = (char*)d_ws;
  size_t o = 0;
  unsigned short* srcb  = (unsigned short*)(wsb+o); o += (size_t)NVROWS*D*2;
  unsigned short* valwt = (unsigned short*)(wsb+o); o += (size_t)NLAY*D*D*2;
  float* value = (float*)(wsb+o); o += (size_t)NVROWS*D*4;
  float* pA    = (float*)(wsb+o); o += BSZ*CHK*D*4;
  float* pD    = (float*)(wsb+o); o += BSZ*CHK*D*4;
  float* tA    = (float*)(wsb+o); o += BSZ*D*4;
  float* tD    = (float*)(wsb+o); o += BSZ*D*4;
  float* cAB   = (float*)(wsb+o); o += 16*4;
  float* refp  = (float*)(wsb+o); o += NQ*2*4;
  float* outb  = (float*)(wsb+o); o += (size_t)NROWS*D*4;
  float* qh    = (float*)(wsb+o); o += (size_t)NROWS*D*4;
  float* kh    = (float*)(wsb+o); o += (size_t)NROWS*D*4;
  float* vh    = (float*)(wsb+o); o += (size_t)NROWS*D*4;
  float* tmpa  = (float*)(wsb+o); o += (size_t)NROWS*D*4;
  float* tmpb  = (float*)(wsb+o); o += (size_t)NROWS*D*4;
  float* ffh   = (float*)(wsb+o); o += (size_t)NROWS*FFD*4;

  colsum_partial<<<BSZ*CHK,256,0,stream>>>(aps,dvs,pA,pD);
  gate_prep<<<BSZ,256,0,stream>>>(pA,pD,aps_w1,aps_b1,aps_w2,aps_b2,
                                  dvs_w1,dvs_b1,dvs_w2,dvs_b2,tA,tD,cAB);
  gate_src<<<NVROWS/4,256,0,stream>>>(aps,dvs,tA,tD,cAB,srcb);
  wconv<<<NLAY*64,256,0,stream>>>(valw,valwt);
  init_out_ref<<<NQ,256,0,stream>>>(qe,ref_w,ref_b,outb,refp,out);

  dim3 g19(4,(NROWS+63)/64);          // N=256, M=1200
  dim3 gmv(NVROWS/128,2);             // MFMA value GEMM
  dim3 gf1(FFD/64,(NROWS+63)/64);     // FFN up

  for(int l=0;l<NLAY;++l){
    const float* Wqkv = saqkvw + (size_t)l*D*3*D;
    const float* bqkv = saqkvb + (size_t)l*3*D;
    gemm64<<<g19,256,0,stream>>>(outb,qe,Wqkv,       bqkv,       qh,NROWS,D,D,3*D,0);
    gemm64<<<g19,256,0,stream>>>(outb,qe,Wqkv+D,     bqkv+D,     kh,NROWS,D,D,3*D,0);
    gemm64<<<g19,256,0,stream>>>(outb,nullptr,Wqkv+2*D,bqkv+2*D, vh,NROWS,D,D,3*D,0);
    self_attn<<<BSZ*NHD*NQ/4,256,0,stream>>>(qh,kh,vh,tmpa);
    gemm64<<<g19,256,0,stream>>>(tmpa,nullptr,saoutw+(size_t)l*D*D,saoutb+(size_t)l*D,tmpb,NROWS,D,D,D,0);
    residual_ln<<<NROWS,256,0,stream>>>(outb,tmpb,ln2w+(size_t)l*D,ln2b+(size_t)l*D,outb);

    // cross attention
    mfma_value<<<gmv,256,0,stream>>>(srcb, valwt+(size_t)l*D*D, valb+(size_t)l*D, mask, value);
    deform_attn<<<NROWS,256,0,stream>>>(outb,qe,
                                        offw+(size_t)l*D*64, offb+(size_t)l*64,
                                        attnw+(size_t)l*D*32, attnb+(size_t)l*32,
                                        value,refp,vr,sshape,tmpa);
    gemm64<<<g19,256,0,stream>>>(tmpa,nullptr,coutw+(size_t)l*D*D,coutb+(size_t)l*D,tmpb,NROWS,D,D,D,0);
    residual_ln<<<NROWS,256,0,stream>>>(outb,tmpb,ln1w+(size_t)l*D,ln1b+(size_t)l*D,outb);

    // FFN
    gemm64<<<gf1,256,0,stream>>>(outb,nullptr,ffw1+(size_t)l*D*FFD,ffb1+(size_t)l*FFD,ffh,NROWS,D,FFD,FFD,1);
    gemm64<<<g19,256,0,stream>>>(ffh,nullptr,ffw2+(size_t)l*FFD*D,ffb2+(size_t)l*D,tmpb,NROWS,FFD,D,D,0);
    residual_ln<<<NROWS,256,0,stream>>>(outb,tmpb,ln3w+(size_t)l*D,ln3b+(size_t)l*D,
                                        (l==NLAY-1)? out : outb);
  }
}

// Round 4
// 872.822 us; speedup vs baseline: 3.6740x; 2.2597x over previous
//
#include <hip/hip_runtime.h>
#include <math.h>

#define D 256
#define NHD 8
#define HDIM 32
#define NPTS 4
#define NLAY 6
#define FFD 1024
#define BSZ 4
#define NSRC 9216
#define NQ 300
#define NROWS (BSZ*NQ)      // 1200
#define NVROWS (BSZ*NSRC)   // 36864
#define CHK 32
#define LNEPS 1e-5f

typedef __attribute__((ext_vector_type(8))) short short8v;
typedef __attribute__((ext_vector_type(4))) float f32x4;

__device__ __forceinline__ unsigned short f2bf(float f){
  unsigned u = __float_as_uint(f);
  unsigned r = (u + 0x7FFFu + ((u>>16)&1u)) >> 16;
  return (unsigned short)r;
}

// ---------------- reduction helpers ----------------
__device__ __forceinline__ float wred_sum(float v){
#pragma unroll
  for(int o=32;o>=1;o>>=1) v += __shfl_xor(v,o,64);
  return v;
}
__device__ __forceinline__ float bred_sum(float v, float* s){
  v = wred_sum(v);
  int lane = threadIdx.x & 63, wid = threadIdx.x >> 6;
  if(lane==0) s[wid]=v;
  __syncthreads();
  float r = s[0]+s[1]+s[2]+s[3];
  __syncthreads();
  return r;
}

// ---------------- gating front-end ----------------
__global__ void colsum_partial(const float* __restrict__ aps, const float* __restrict__ dvs,
                               float* __restrict__ pA, float* __restrict__ pD){
  int blk = blockIdx.x; int b = blk / CHK; int c = blk % CHK;
  int d = threadIdx.x;
  const int rows = NSRC / CHK;   // 288
  float sa=0.f, sd=0.f;
  size_t base = (size_t)b*NSRC*D + (size_t)(c*rows)*D + d;
  for(int r=0;r<rows;++r){
    sa += aps[base + (size_t)r*D];
    sd += dvs[base + (size_t)r*D];
  }
  pA[(b*CHK+c)*D + d] = sa;
  pD[(b*CHK+c)*D + d] = sd;
}

__global__ void gate_prep(const float* __restrict__ pA, const float* __restrict__ pD,
                          const float* __restrict__ w1a, const float* __restrict__ b1a,
                          const float* __restrict__ w2a, const float* __restrict__ b2a,
                          const float* __restrict__ w1d, const float* __restrict__ b1d,
                          const float* __restrict__ w2d, const float* __restrict__ b2d,
                          float* __restrict__ tA, float* __restrict__ tD, float* __restrict__ cAB){
  __shared__ float sumA[D], sumD[D], s2A[D], s2D[D], red[4];
  int b = blockIdx.x, t = threadIdx.x;
  float sa=0.f, sd=0.f;
  for(int c=0;c<CHK;++c){ sa += pA[(b*CHK+c)*D+t]; sd += pD[(b*CHK+c)*D+t]; }
  sumA[t]=sa; sumD[t]=sd;
  __syncthreads();
  float va=0.f, vd=0.f;
  for(int i=0;i<D;++i){ va += sumA[i]*w2a[i*D+t]; vd += sumD[i]*w2d[i*D+t]; }
  s2A[t] = va + (float)NSRC * b2a[t];
  s2D[t] = vd + (float)NSRC * b2d[t];
  __syncthreads();
  float ta=0.f, td=0.f;
  for(int j=0;j<D;++j){ ta += w1a[t*D+j]*s2A[j]; td += w1d[t*D+j]*s2D[j]; }
  tA[b*D+t]=ta; tD[b*D+t]=td;
  float ca = bred_sum(b1a[t]*s2A[t], red);
  float cd = bred_sum(b1d[t]*s2D[t], red);
  if(t==0){ cAB[b]=ca; cAB[BSZ+b]=cd; }
}

// per-row gate softmax + fused src (emits bf16)
__global__ void gate_src(const float* __restrict__ aps, const float* __restrict__ dvs,
                         const float* __restrict__ tA, const float* __restrict__ tD,
                         const float* __restrict__ cAB, unsigned short* __restrict__ srcb){
  int w = threadIdx.x >> 6, lane = threadIdx.x & 63;
  size_t row = (size_t)blockIdx.x*4 + w;
  int b = (int)(row / NSRC);
  const float4* ap = (const float4*)(aps + row*D);
  const float4* dp = (const float4*)(dvs + row*D);
  const float4* tap = (const float4*)(tA + (size_t)b*D);
  const float4* tdp = (const float4*)(tD + (size_t)b*D);
  float4 a = ap[lane], dd = dp[lane], ta = tap[lane], td = tdp[lane];
  float ga = a.x*ta.x + a.y*ta.y + a.z*ta.z + a.w*ta.w;
  float gd = dd.x*td.x + dd.y*td.y + dd.z*td.z + dd.w*td.w;
  ga = (wred_sum(ga) + cAB[b]) * 0.0625f;       // 1/sqrt(256)
  gd = (wred_sum(gd) + cAB[BSZ+b]) * 0.0625f;
  float m = fmaxf(ga,gd);
  float ea = expf(ga-m), ed = expf(gd-m);
  float inv = 1.f/(ea+ed);
  float wa = ea*inv, wd = ed*inv;
  ushort4 o;
  o.x = f2bf(wa*a.x + wd*dd.x); o.y = f2bf(wa*a.y + wd*dd.y);
  o.z = f2bf(wa*a.z + wd*dd.z); o.w = f2bf(wa*a.w + wd*dd.w);
  ((ushort4*)(srcb + row*D))[lane] = o;
}

// generic weight transpose+convert: Bt[l][n][k] = bf16(W[l][k][n])
__global__ void wconvT(const float* __restrict__ W, unsigned short* __restrict__ Bt,
                       int K, int N){
  __shared__ float tile[32][33];
  int l = blockIdx.y;
  int nk = K>>5;
  int tk = blockIdx.x % nk, tn = blockIdx.x / nk;
  int tx = threadIdx.x & 31, ty = threadIdx.x >> 5;
  const float* Wl = W + (size_t)l*K*N;
  unsigned short* Btl = Bt + (size_t)l*N*K;
#pragma unroll
  for(int i=0;i<4;++i)
    tile[ty+i*8][tx] = Wl[(size_t)(tk*32+ty+i*8)*N + tn*32+tx];
  __syncthreads();
#pragma unroll
  for(int i=0;i<4;++i)
    Btl[(size_t)(tn*32+ty+i*8)*K + tk*32+tx] = f2bf(tile[tx][ty+i*8]);
}

__global__ void init_out_ref(const float* __restrict__ qe, const float* __restrict__ refw,
                             const float* __restrict__ refb,
                             float* __restrict__ outb, unsigned short* __restrict__ out_bf,
                             unsigned short* __restrict__ outpos_bf,
                             float* __restrict__ refp, float* __restrict__ dout){
  __shared__ float red[4];
  int q = blockIdx.x, t = threadIdx.x;
  float pos = qe[(size_t)q*2*D + t];
  float tgt = qe[(size_t)q*2*D + D + t];
  unsigned short tb = f2bf(tgt), tpb = f2bf(tgt+pos);
  for(int b=0;b<BSZ;++b){
    outb[((size_t)b*NQ+q)*D + t] = tgt;
    out_bf[((size_t)b*NQ+q)*D + t] = tb;
    outpos_bf[((size_t)b*NQ+q)*D + t] = tpb;
  }
  float d0 = bred_sum(pos*refw[t*2+0], red);
  float d1 = bred_sum(pos*refw[t*2+1], red);
  if(t<2){
    float dot = (t==0? d0 : d1) + refb[t];
    float r = 1.f/(1.f+expf(-dot));
    refp[q*2+t] = r;
    const size_t o1 = (size_t)BSZ*NQ*D;
    const size_t o2 = o1 + (size_t)BSZ*NQ*2;
    for(int b=0;b<BSZ;++b){
      dout[o1 + (b*NQ+q)*2 + t] = r;
      dout[o2 + (b*NQ+q)*2 + t] = r;
    }
  }
}

// ---------------- unified bf16 MFMA GEMM (M-chain), 64x64 tile ----------------
__global__ __launch_bounds__(256) void gemmb(
    const unsigned short* __restrict__ A,   // [M][K] bf16
    const unsigned short* __restrict__ Bt,  // [N][K] bf16
    const float* __restrict__ bias,
    float* __restrict__ Cf, unsigned short* __restrict__ Cb,
    int M, int K, int N, int relu){
  __shared__ unsigned short As[64][40];
  __shared__ unsigned short Bs[64][40];
  int n0 = blockIdx.x*64, m0 = blockIdx.y*64;
  int t = threadIdx.x, wave = t>>6, lane = t&63;
  int wm = (wave>>1)*32, wn = (wave&1)*32;
  int hi = lane>>4, lo = lane&15;
  int sr = t>>2, sc = (t&3)*8;
  f32x4 acc[2][2];
#pragma unroll
  for(int i=0;i<2;++i)
#pragma unroll
    for(int j=0;j<2;++j)
#pragma unroll
      for(int r=0;r<4;++r) acc[i][j][r]=0.f;
  for(int k0=0;k0<K;k0+=32){
    uint4 av = make_uint4(0,0,0,0);
    int arow = m0+sr;
    if(arow < M) av = *(const uint4*)(A + (size_t)arow*K + k0 + sc);
    *(uint4*)&As[sr][sc] = av;
    *(uint4*)&Bs[sr][sc] = *(const uint4*)(Bt + (size_t)(n0+sr)*K + k0 + sc);
    __syncthreads();
    short8v a0 = *(short8v*)&As[wm+lo][hi*8];
    short8v a1 = *(short8v*)&As[wm+16+lo][hi*8];
    short8v b0 = *(short8v*)&Bs[wn+lo][hi*8];
    short8v b1 = *(short8v*)&Bs[wn+16+lo][hi*8];
    acc[0][0] = __builtin_amdgcn_mfma_f32_16x16x32_bf16(a0,b0,acc[0][0],0,0,0);
    acc[0][1] = __builtin_amdgcn_mfma_f32_16x16x32_bf16(a0,b1,acc[0][1],0,0,0);
    acc[1][0] = __builtin_amdgcn_mfma_f32_16x16x32_bf16(a1,b0,acc[1][0],0,0,0);
    acc[1][1] = __builtin_amdgcn_mfma_f32_16x16x32_bf16(a1,b1,acc[1][1],0,0,0);
    __syncthreads();
  }
#pragma unroll
  for(int mf=0;mf<2;++mf){
#pragma unroll
    for(int nf=0;nf<2;++nf){
      int col = n0 + wn + nf*16 + lo;
      float bv = bias[col];
#pragma unroll
      for(int r=0;r<4;++r){
        int row = m0 + wm + mf*16 + hi*4 + r;
        if(row < M){
          float v = acc[mf][nf][r] + bv;
          if(relu) v = fmaxf(v, 0.f);
          if(Cf) Cf[(size_t)row*N+col] = v;
          if(Cb) Cb[(size_t)row*N+col] = f2bf(v);
        }
      }
    }
  }
}

// ---------------- bf16 MFMA value GEMM (M=36864), 128x128 tile ----------------
__global__ __launch_bounds__(256) void mfma_value(
    const unsigned short* __restrict__ Abf,   // [M][256] bf16
    const unsigned short* __restrict__ Bt,    // [256][256] bf16, Bt[n][k]
    const float* __restrict__ bias, const unsigned char* __restrict__ rowmask,
    float* __restrict__ C){
  __shared__ unsigned short As[128][40];
  __shared__ unsigned short Bs[128][40];
  int m0 = blockIdx.x*128, n0 = blockIdx.y*128;
  int t = threadIdx.x;
  int wave = t>>6, lane = t&63;
  int wm = (wave>>1)*64, wn = (wave&1)*64;
  f32x4 acc[4][4];
#pragma unroll
  for(int i=0;i<4;++i)
#pragma unroll
    for(int j=0;j<4;++j)
#pragma unroll
      for(int r=0;r<4;++r) acc[i][j][r]=0.f;

  int r0 = t>>2, c0 = (t&3)*8;
  int r1 = (t+256)>>2;
  for(int k0=0;k0<256;k0+=32){
    *(uint4*)&As[r0][c0] = *(const uint4*)(Abf + (size_t)(m0+r0)*256 + k0 + c0);
    *(uint4*)&As[r1][c0] = *(const uint4*)(Abf + (size_t)(m0+r1)*256 + k0 + c0);
    *(uint4*)&Bs[r0][c0] = *(const uint4*)(Bt  + (size_t)(n0+r0)*256 + k0 + c0);
    *(uint4*)&Bs[r1][c0] = *(const uint4*)(Bt  + (size_t)(n0+r1)*256 + k0 + c0);
    __syncthreads();
    short8v a[4], bb[4];
#pragma unroll
    for(int mf=0;mf<4;++mf) a[mf]  = *(short8v*)&As[wm+mf*16+(lane&15)][(lane>>4)*8];
#pragma unroll
    for(int nf=0;nf<4;++nf) bb[nf] = *(short8v*)&Bs[wn+nf*16+(lane&15)][(lane>>4)*8];
#pragma unroll
    for(int mf=0;mf<4;++mf)
#pragma unroll
      for(int nf=0;nf<4;++nf)
        acc[mf][nf] = __builtin_amdgcn_mfma_f32_16x16x32_bf16(a[mf], bb[nf], acc[mf][nf], 0,0,0);
    __syncthreads();
  }
#pragma unroll
  for(int mf=0;mf<4;++mf){
    int rbase = m0 + wm + mf*16 + (lane>>4)*4;
#pragma unroll
    for(int nf=0;nf<4;++nf){
      int col = n0 + wn + nf*16 + (lane&15);
      float bv = bias[col];
#pragma unroll
      for(int r=0;r<4;++r){
        int row = rbase + r;
        float v = acc[mf][nf][r] + bv;
        if(rowmask[row]) v = 0.f;
        C[(size_t)row*256 + col] = v;
      }
    }
  }
}

// ---------------- MFMA self attention: block = (b,h) x 64-row Q tile --------
__global__ __launch_bounds__(256) void self_attn_mfma(
    const unsigned short* __restrict__ qkh,  // [1200][512] bf16 (q|k)
    const unsigned short* __restrict__ vh,   // [1200][256] bf16
    unsigned short* __restrict__ sa){        // [1200][256] bf16
  __shared__ unsigned short P[64][328];
  __shared__ unsigned short Vt[32][328];
  int blk = blockIdx.x;
  int qt = blk % 5; int bh = blk / 5; int h = bh % NHD; int b = bh / NHD;
  int t = threadIdx.x, wv = t>>6, lane = t&63;
  int hi = lane>>4, lo = lane&15;
  // stage Vt[c][k] = vh[b*300+k][h*32+c], zero-pad k>=300
  {
    int c = t & 31, rb = t >> 5;
    for(int r = rb; r < 320; r += 8){
      unsigned short v = 0;
      if(r < 300) v = vh[(size_t)(b*300+r)*256 + h*32 + c];
      Vt[c][r] = v;
    }
  }
  __syncthreads();
  int m0 = qt*64 + wv*16;
  // Q fragment (rows clamped; rows>=300 never stored)
  int qr = m0 + lo; if(qr > 299) qr = 299;
  short8v aq = *(const short8v*)(qkh + (size_t)(b*300+qr)*512 + h*32 + hi*8);
  // S = Q@K^T over 19 col-tiles
  f32x4 s[19];
#pragma unroll
  for(int nt=0; nt<19; ++nt){
    int kr = nt*16 + lo; if(kr > 299) kr = 299;
    short8v bk = *(const short8v*)(qkh + (size_t)(b*300+kr)*512 + 256 + h*32 + hi*8);
    f32x4 z; z[0]=0.f; z[1]=0.f; z[2]=0.f; z[3]=0.f;
    s[nt] = __builtin_amdgcn_mfma_f32_16x16x32_bf16(aq, bk, z, 0,0,0);
  }
  // softmax per row (row = hi*4+ri within strip; col = nt*16+lo)
  const float kSc = 0.25506009837f;   // (1/sqrt(32)) * log2(e)
  float inv[4];
#pragma unroll
  for(int ri=0; ri<4; ++ri){
    float m = -1e30f;
#pragma unroll
    for(int nt=0; nt<19; ++nt){
      if(nt*16+lo < 300) m = fmaxf(m, s[nt][ri]);
    }
#pragma unroll
    for(int o=8;o>=1;o>>=1) m = fmaxf(m, __shfl_xor(m,o,64));
    float sum = 0.f;
#pragma unroll
    for(int nt=0; nt<19; ++nt){
      float p = 0.f;
      if(nt*16+lo < 300) p = exp2f((s[nt][ri]-m)*kSc);
      sum += p;
      P[wv*16 + hi*4 + ri][nt*16 + lo] = f2bf(p);
    }
    P[wv*16 + hi*4 + ri][304 + lo] = 0;   // zero pad cols 304..319
#pragma unroll
    for(int o=8;o>=1;o>>=1) sum += __shfl_xor(sum,o,64);
    inv[ri] = 1.f/sum;
  }
  // PV: O[16x32] = P[16x320] @ V[320x32]
  f32x4 o0, o1;
#pragma unroll
  for(int r=0;r<4;++r){ o0[r]=0.f; o1[r]=0.f; }
#pragma unroll
  for(int kt=0; kt<10; ++kt){
    short8v ap = *(short8v*)&P[wv*16 + lo][kt*32 + hi*8];
    short8v b0 = *(short8v*)&Vt[lo][kt*32 + hi*8];
    short8v b1 = *(short8v*)&Vt[16+lo][kt*32 + hi*8];
    o0 = __builtin_amdgcn_mfma_f32_16x16x32_bf16(ap, b0, o0, 0,0,0);
    o1 = __builtin_amdgcn_mfma_f32_16x16x32_bf16(ap, b1, o1, 0,0,0);
  }
#pragma unroll
  for(int ri=0; ri<4; ++ri){
    int r = m0 + hi*4 + ri;
    if(r < 300){
      size_t base = (size_t)(b*300+r)*256 + h*32;
      sa[base + lo]      = f2bf(o0[ri]*inv[ri]);
      sa[base + 16 + lo] = f2bf(o1[ri]*inv[ri]);
    }
  }
}

// ---------------- residual + layernorm (+ optional bf16 emissions) ----------
__global__ void residual_ln(const float* __restrict__ base, const float* __restrict__ delta,
                            const float* __restrict__ w, const float* __restrict__ bvec,
                            float* __restrict__ dstf, unsigned short* __restrict__ dstb,
                            unsigned short* __restrict__ dstp, const float* __restrict__ qe){
  __shared__ float red[4];
  size_t row = blockIdx.x; int t = threadIdx.x;
  float v = base[row*D+t] + delta[row*D+t];
  float mean = bred_sum(v, red) * (1.f/D);
  float c = v - mean;
  float var = bred_sum(c*c, red) * (1.f/D);
  float y = c * rsqrtf(var + LNEPS) * w[t] + bvec[t];
  dstf[row*D+t] = y;
  if(dstb) dstb[row*D+t] = f2bf(y);
  if(dstp){
    int q = (int)(row % NQ);
    dstp[row*D+t] = f2bf(y + qe[(size_t)q*2*D + t]);
  }
}

// ---------------- fused deformable cross-attn (emits bf16) ------------------
__global__ void deform_attn(const float* __restrict__ outb, const float* __restrict__ qe,
                            const float* __restrict__ offw, const float* __restrict__ offb,
                            const float* __restrict__ attnw, const float* __restrict__ attnb,
                            const float* __restrict__ value, const float* __restrict__ refp,
                            const float* __restrict__ vr, const int* __restrict__ sshape,
                            unsigned short* __restrict__ ca){
  __shared__ float qrow[D];
  __shared__ float part[96][2];
  __shared__ float proj[96];
  int row = blockIdx.x; int b = row / NQ; int q = row % NQ;
  int t = threadIdx.x;
  qrow[t] = outb[(size_t)row*D + t] + qe[(size_t)q*2*D + t];
  __syncthreads();
  if(t < 192){
    int col = t >> 1, half = t & 1;
    float acc = 0.f;
    if(col < 64){
      const float* W = offw;
      for(int k=half*128; k<half*128+128; ++k) acc += qrow[k]*W[(size_t)k*64 + col];
    } else {
      const float* W = attnw; int c = col-64;
      for(int k=half*128; k<half*128+128; ++k) acc += qrow[k]*W[(size_t)k*32 + c];
    }
    part[col][half] = acc;
  }
  __syncthreads();
  if(t < 96) proj[t] = part[t][0] + part[t][1] + (t<64 ? offb[t] : attnb[t-64]);
  __syncthreads();

  int h = t>>5, hd = t&31;
  float Hf = (float)sshape[0], Wf = (float)sshape[1];
  int Ws = sshape[1];
  float rx = refp[q*2+0] * vr[b*2+0];
  float ry = refp[q*2+1] * vr[b*2+1];
  const float* lg = &proj[64 + h*4];
  float m = fmaxf(fmaxf(lg[0],lg[1]),fmaxf(lg[2],lg[3]));
  float e[4]; float esum=0.f;
#pragma unroll
  for(int p=0;p<4;++p){ e[p]=expf(lg[p]-m); esum+=e[p]; }
  float einv = 1.f/esum;
  const float* ofr = &proj[h*8];
  const float* vbase = value + ((size_t)b*NSRC)*D + h*HDIM + hd;
  float acc = 0.f;
#pragma unroll
  for(int p=0;p<NPTS;++p){
    float lx = rx + ofr[p*2+0]/Wf;
    float ly = ry + ofr[p*2+1]/Hf;
    float x = lx*Wf - 0.5f, y = ly*Hf - 0.5f;
    float x0 = floorf(x), y0 = floorf(y);
    float wx = x-x0, wy = y-y0;
    float sample = 0.f;
#pragma unroll
    for(int cy=0;cy<2;++cy){
#pragma unroll
      for(int cx=0;cx<2;++cx){
        float xi = x0+cx, yi = y0+cy;
        float wgt = (cx? wx : 1.f-wx) * (cy? wy : 1.f-wy);
        bool valid = (xi>=0.f)&&(xi<=Wf-1.f)&&(yi>=0.f)&&(yi<=Hf-1.f);
        if(valid){
          int idx = (int)fminf(fmaxf(yi,0.f),Hf-1.f)*Ws + (int)fminf(fmaxf(xi,0.f),Wf-1.f);
          sample += wgt * vbase[(size_t)idx*D];
        }
      }
    }
    acc += (e[p]*einv) * sample;
  }
  ca[(size_t)row*D + h*HDIM + hd] = f2bf(acc);
}

// ---------------- host ----------------
extern "C" void kernel_launch(void* const* d_in, const int* in_sizes, int n_in,
                              void* d_out, int out_size, void* d_ws, size_t ws_size,
                              hipStream_t stream){
  const float* aps=(const float*)d_in[0];
  const float* dvs=(const float*)d_in[1];
  const float* qe =(const float*)d_in[2];
  const float* vr =(const float*)d_in[3];
  const float* aps_w1=(const float*)d_in[4]; const float* aps_b1=(const float*)d_in[5];
  const float* aps_w2=(const float*)d_in[6]; const float* aps_b2=(const float*)d_in[7];
  const float* dvs_w1=(const float*)d_in[8]; const float* dvs_b1=(const float*)d_in[9];
  const float* dvs_w2=(const float*)d_in[10]; const float* dvs_b2=(const float*)d_in[11];
  const float* ref_w=(const float*)d_in[12]; const float* ref_b=(const float*)d_in[13];
  const float* saqkvw=(const float*)d_in[14]; const float* saqkvb=(const float*)d_in[15];
  const float* saoutw=(const float*)d_in[16]; const float* saoutb=(const float*)d_in[17];
  const float* offw=(const float*)d_in[18]; const float* offb=(const float*)d_in[19];
  const float* attnw=(const float*)d_in[20]; const float* attnb=(const float*)d_in[21];
  const float* valw=(const float*)d_in[22]; const float* valb=(const float*)d_in[23];
  const float* coutw=(const float*)d_in[24]; const float* coutb=(const float*)d_in[25];
  const float* ln1w=(const float*)d_in[26]; const float* ln1b=(const float*)d_in[27];
  const float* ln2w=(const float*)d_in[28]; const float* ln2b=(const float*)d_in[29];
  const float* ln3w=(const float*)d_in[30]; const float* ln3b=(const float*)d_in[31];
  const float* ffw1=(const float*)d_in[32]; const float* ffb1=(const float*)d_in[33];
  const float* ffw2=(const float*)d_in[34]; const float* ffb2=(const float*)d_in[35];
  const unsigned char* mask=(const unsigned char*)d_in[36];
  const int* sshape=(const int*)d_in[37];
  float* out = (float*)d_out;

  char* wsb = (char*)d_ws;
  size_t o = 0;
  unsigned short* srcb   = (unsigned short*)(wsb+o); o += (size_t)NVROWS*D*2;
  unsigned short* valT   = (unsigned short*)(wsb+o); o += (size_t)NLAY*D*D*2;
  unsigned short* qkvT   = (unsigned short*)(wsb+o); o += (size_t)NLAY*3*D*D*2;
  unsigned short* saoutT = (unsigned short*)(wsb+o); o += (size_t)NLAY*D*D*2;
  unsigned short* coutT  = (unsigned short*)(wsb+o); o += (size_t)NLAY*D*D*2;
  unsigned short* ff1T   = (unsigned short*)(wsb+o); o += (size_t)NLAY*D*FFD*2;
  unsigned short* ff2T   = (unsigned short*)(wsb+o); o += (size_t)NLAY*FFD*D*2;
  float* value = (float*)(wsb+o); o += (size_t)NVROWS*D*4;
  float* pA    = (float*)(wsb+o); o += BSZ*CHK*D*4;
  float* pD    = (float*)(wsb+o); o += BSZ*CHK*D*4;
  float* tA    = (float*)(wsb+o); o += BSZ*D*4;
  float* tD    = (float*)(wsb+o); o += BSZ*D*4;
  float* cAB   = (float*)(wsb+o); o += 16*4;
  float* refp  = (float*)(wsb+o); o += NQ*2*4;
  float* outb  = (float*)(wsb+o); o += (size_t)NROWS*D*4;
  float* tmpb  = (float*)(wsb+o); o += (size_t)NROWS*D*4;
  unsigned short* out_bf    = (unsigned short*)(wsb+o); o += (size_t)NROWS*D*2;
  unsigned short* outpos_bf = (unsigned short*)(wsb+o); o += (size_t)NROWS*D*2;
  unsigned short* qkh_bf    = (unsigned short*)(wsb+o); o += (size_t)NROWS*2*D*2;
  unsigned short* vh_bf     = (unsigned short*)(wsb+o); o += (size_t)NROWS*D*2;
  unsigned short* sa_bf     = (unsigned short*)(wsb+o); o += (size_t)NROWS*D*2;
  unsigned short* ca_bf     = (unsigned short*)(wsb+o); o += (size_t)NROWS*D*2;
  unsigned short* ffh_bf    = (unsigned short*)(wsb+o); o += (size_t)NROWS*FFD*2;

  // ---- prologue
  colsum_partial<<<BSZ*CHK,256,0,stream>>>(aps,dvs,pA,pD);
  gate_prep<<<BSZ,256,0,stream>>>(pA,pD,aps_w1,aps_b1,aps_w2,aps_b2,
                                  dvs_w1,dvs_b1,dvs_w2,dvs_b2,tA,tD,cAB);
  gate_src<<<NVROWS/4,256,0,stream>>>(aps,dvs,tA,tD,cAB,srcb);
  wconvT<<<dim3(8*8,  NLAY),256,0,stream>>>(valw,   valT,   D, D);
  wconvT<<<dim3(8*24, NLAY),256,0,stream>>>(saqkvw, qkvT,   D, 3*D);
  wconvT<<<dim3(8*8,  NLAY),256,0,stream>>>(saoutw, saoutT, D, D);
  wconvT<<<dim3(8*8,  NLAY),256,0,stream>>>(coutw,  coutT,  D, D);
  wconvT<<<dim3(8*32, NLAY),256,0,stream>>>(ffw1,   ff1T,   D, FFD);
  wconvT<<<dim3(32*8, NLAY),256,0,stream>>>(ffw2,   ff2T,   FFD, D);
  init_out_ref<<<NQ,256,0,stream>>>(qe,ref_w,ref_b,outb,out_bf,outpos_bf,refp,out);

  dim3 gqk(8,19), g256(4,19), gffu(16,19);
  dim3 gmv(NVROWS/128,2);

  for(int l=0;l<NLAY;++l){
    const unsigned short* qkvTl = qkvT + (size_t)l*3*D*D;
    const float* bqkv = saqkvb + (size_t)l*3*D;
    // self attention
    gemmb<<<gqk ,256,0,stream>>>(outpos_bf, qkvTl,         bqkv,       nullptr, qkh_bf, NROWS, D, 2*D, 0);
    gemmb<<<g256,256,0,stream>>>(out_bf,    qkvTl+2*D*D,   bqkv+2*D,   nullptr, vh_bf,  NROWS, D, D,   0);
    self_attn_mfma<<<BSZ*NHD*5,256,0,stream>>>(qkh_bf, vh_bf, sa_bf);
    gemmb<<<g256,256,0,stream>>>(sa_bf, saoutT+(size_t)l*D*D, saoutb+(size_t)l*D, tmpb, nullptr, NROWS, D, D, 0);
    residual_ln<<<NROWS,256,0,stream>>>(outb,tmpb,ln2w+(size_t)l*D,ln2b+(size_t)l*D, outb,nullptr,nullptr,qe);

    // deformable cross attention
    mfma_value<<<gmv,256,0,stream>>>(srcb, valT+(size_t)l*D*D, valb+(size_t)l*D, mask, value);
    deform_attn<<<NROWS,256,0,stream>>>(outb,qe,
                                        offw+(size_t)l*D*64, offb+(size_t)l*64,
                                        attnw+(size_t)l*D*32, attnb+(size_t)l*32,
                                        value,refp,vr,sshape,ca_bf);
    gemmb<<<g256,256,0,stream>>>(ca_bf, coutT+(size_t)l*D*D, coutb+(size_t)l*D, tmpb, nullptr, NROWS, D, D, 0);
    residual_ln<<<NROWS,256,0,stream>>>(outb,tmpb,ln1w+(size_t)l*D,ln1b+(size_t)l*D, outb,out_bf,nullptr,qe);

    // FFN
    gemmb<<<gffu,256,0,stream>>>(out_bf, ff1T+(size_t)l*D*FFD, ffb1+(size_t)l*FFD, nullptr, ffh_bf, NROWS, D, FFD, 1);
    gemmb<<<g256,256,0,stream>>>(ffh_bf, ff2T+(size_t)l*FFD*D, ffb2+(size_t)l*D, tmpb, nullptr, NROWS, FFD, D, 0);
    if(l==NLAY-1)
      residual_ln<<<NROWS,256,0,stream>>>(outb,tmpb,ln3w+(size_t)l*D,ln3b+(size_t)l*D, out,nullptr,nullptr,qe);
    else
      residual_ln<<<NROWS,256,0,stream>>>(outb,tmpb,ln3w+(size_t)l*D,ln3b+(size_t)l*D, outb,out_bf,outpos_bf,qe);
  }
}

// Round 5
// 771.354 us; speedup vs baseline: 4.1573x; 1.1315x over previous
//
#include <hip/hip_runtime.h>
#include <math.h>

#define D 256
#define NHD 8
#define HDIM 32
#define NPTS 4
#define NLAY 6
#define FFD 1024
#define BSZ 4
#define NSRC 9216
#define NQ 300
#define NROWS (BSZ*NQ)      // 1200
#define NVROWS (BSZ*NSRC)   // 36864
#define CHK 32
#define LNEPS 1e-5f

typedef __attribute__((ext_vector_type(8))) short short8v;
typedef __attribute__((ext_vector_type(4))) float f32x4;

__device__ __forceinline__ unsigned short f2bf(float f){
  unsigned u = __float_as_uint(f);
  unsigned r = (u + 0x7FFFu + ((u>>16)&1u)) >> 16;
  return (unsigned short)r;
}
__device__ __forceinline__ float bf2f(unsigned short u){
  return __uint_as_float(((unsigned)u)<<16);
}

// ---------------- reduction helpers ----------------
__device__ __forceinline__ float wred_sum(float v){
#pragma unroll
  for(int o=32;o>=1;o>>=1) v += __shfl_xor(v,o,64);
  return v;
}
__device__ __forceinline__ float bred_sum(float v, float* s){
  v = wred_sum(v);
  int lane = threadIdx.x & 63, wid = threadIdx.x >> 6;
  if(lane==0) s[wid]=v;
  __syncthreads();
  float r = s[0]+s[1]+s[2]+s[3];
  __syncthreads();
  return r;
}

// ---------------- gating front-end ----------------
__global__ void colsum_partial(const float* __restrict__ aps, const float* __restrict__ dvs,
                               float* __restrict__ pA, float* __restrict__ pD){
  int blk = blockIdx.x; int b = blk / CHK; int c = blk % CHK;
  int d = threadIdx.x;
  const int rows = NSRC / CHK;   // 288
  float sa=0.f, sd=0.f;
  size_t base = (size_t)b*NSRC*D + (size_t)(c*rows)*D + d;
  for(int r=0;r<rows;++r){
    sa += aps[base + (size_t)r*D];
    sd += dvs[base + (size_t)r*D];
  }
  pA[(b*CHK+c)*D + d] = sa;
  pD[(b*CHK+c)*D + d] = sd;
}

// s2 = colsum@W2 + N*b2 ; c = b1.s2   — one block per (b,modality)
__global__ void gate_s2(const float* __restrict__ pA, const float* __restrict__ pD,
                        const float* __restrict__ w2a, const float* __restrict__ b2a,
                        const float* __restrict__ w2d, const float* __restrict__ b2d,
                        const float* __restrict__ b1a, const float* __restrict__ b1d,
                        float* __restrict__ s2, float* __restrict__ cAB){
  __shared__ float sums[D]; __shared__ float red[4];
  int blk = blockIdx.x; int b = blk>>1; int mod = blk&1;
  int t = threadIdx.x;
  const float* pX = mod? pD : pA;
  const float* w2 = mod? w2d : w2a;
  const float* b2 = mod? b2d : b2a;
  const float* b1 = mod? b1d : b1a;
  float s=0.f;
  for(int c=0;c<CHK;++c) s += pX[(b*CHK+c)*D+t];
  sums[t]=s; __syncthreads();
  float v=0.f;
  for(int i=0;i<D;++i) v += sums[i]*w2[(size_t)i*D+t];
  v += (float)NSRC * b2[t];
  s2[(size_t)blk*D + t] = v;
  float c = bred_sum(b1[t]*v, red);
  if(t==0) cAB[mod*BSZ + b] = c;
}

// t = W1 @ s2 — one wave per output element (2048 waves)
__global__ void gate_t(const float* __restrict__ w1a, const float* __restrict__ w1d,
                       const float* __restrict__ s2,
                       float* __restrict__ tA, float* __restrict__ tD){
  int gw = blockIdx.x*4 + (threadIdx.x>>6);
  int lane = threadIdx.x & 63;
  int i = gw & 255; int bm = gw >> 8;      // bm = b*2+mod
  int mod = bm & 1, b = bm >> 1;
  const float* w1 = mod? w1d : w1a;
  const float* s2v = s2 + (size_t)bm*D;
  float4 wv = *(const float4*)(w1 + (size_t)i*D + lane*4);
  float4 sv = *(const float4*)(s2v + lane*4);
  float d = wv.x*sv.x + wv.y*sv.y + wv.z*sv.z + wv.w*sv.w;
  d = wred_sum(d);
  if(lane==0){
    if(mod) tD[b*D+i] = d; else tA[b*D+i] = d;
  }
}

// per-row gate softmax + fused src (emits bf16)
__global__ void gate_src(const float* __restrict__ aps, const float* __restrict__ dvs,
                         const float* __restrict__ tA, const float* __restrict__ tD,
                         const float* __restrict__ cAB, unsigned short* __restrict__ srcb){
  int w = threadIdx.x >> 6, lane = threadIdx.x & 63;
  size_t row = (size_t)blockIdx.x*4 + w;
  int b = (int)(row / NSRC);
  const float4* ap = (const float4*)(aps + row*D);
  const float4* dp = (const float4*)(dvs + row*D);
  const float4* tap = (const float4*)(tA + (size_t)b*D);
  const float4* tdp = (const float4*)(tD + (size_t)b*D);
  float4 a = ap[lane], dd = dp[lane], ta = tap[lane], td = tdp[lane];
  float ga = a.x*ta.x + a.y*ta.y + a.z*ta.z + a.w*ta.w;
  float gd = dd.x*td.x + dd.y*td.y + dd.z*td.z + dd.w*td.w;
  ga = (wred_sum(ga) + cAB[b]) * 0.0625f;       // 1/sqrt(256)
  gd = (wred_sum(gd) + cAB[BSZ+b]) * 0.0625f;
  float m = fmaxf(ga,gd);
  float ea = expf(ga-m), ed = expf(gd-m);
  float inv = 1.f/(ea+ed);
  float wa = ea*inv, wd = ed*inv;
  ushort4 o;
  o.x = f2bf(wa*a.x + wd*dd.x); o.y = f2bf(wa*a.y + wd*dd.y);
  o.z = f2bf(wa*a.z + wd*dd.z); o.w = f2bf(wa*a.w + wd*dd.w);
  ((ushort4*)(srcb + row*D))[lane] = o;
}

// generic weight transpose+convert: Bt[l][n][k] = bf16(W[l][k][n])
__global__ void wconvT(const float* __restrict__ W, unsigned short* __restrict__ Bt,
                       int K, int N){
  __shared__ float tile[32][33];
  int l = blockIdx.y;
  int nk = K>>5;
  int tk = blockIdx.x % nk, tn = blockIdx.x / nk;
  int tx = threadIdx.x & 31, ty = threadIdx.x >> 5;
  const float* Wl = W + (size_t)l*K*N;
  unsigned short* Btl = Bt + (size_t)l*N*K;
#pragma unroll
  for(int i=0;i<4;++i)
    tile[ty+i*8][tx] = Wl[(size_t)(tk*32+ty+i*8)*N + tn*32+tx];
  __syncthreads();
#pragma unroll
  for(int i=0;i<4;++i)
    Btl[(size_t)(tn*32+ty+i*8)*K + tk*32+tx] = f2bf(tile[tx][ty+i*8]);
}

__global__ void init_out_ref(const float* __restrict__ qe, const float* __restrict__ refw,
                             const float* __restrict__ refb,
                             float* __restrict__ outb, unsigned short* __restrict__ out_bf,
                             unsigned short* __restrict__ outpos_bf,
                             float* __restrict__ refp, float* __restrict__ dout){
  __shared__ float red[4];
  int q = blockIdx.x, t = threadIdx.x;
  float pos = qe[(size_t)q*2*D + t];
  float tgt = qe[(size_t)q*2*D + D + t];
  unsigned short tb = f2bf(tgt), tpb = f2bf(tgt+pos);
  for(int b=0;b<BSZ;++b){
    outb[((size_t)b*NQ+q)*D + t] = tgt;
    out_bf[((size_t)b*NQ+q)*D + t] = tb;
    outpos_bf[((size_t)b*NQ+q)*D + t] = tpb;
  }
  float d0 = bred_sum(pos*refw[t*2+0], red);
  float d1 = bred_sum(pos*refw[t*2+1], red);
  if(t<2){
    float dot = (t==0? d0 : d1) + refb[t];
    float r = 1.f/(1.f+expf(-dot));
    refp[q*2+t] = r;
    const size_t o1 = (size_t)BSZ*NQ*D;
    const size_t o2 = o1 + (size_t)BSZ*NQ*2;
    for(int b=0;b<BSZ;++b){
      dout[o1 + (b*NQ+q)*2 + t] = r;
      dout[o2 + (b*NQ+q)*2 + t] = r;
    }
  }
}

// ---------------- unified bf16 MFMA GEMM (M-chain), 64x64 tile ----------------
// A2/ncut: column blocks with n0>=ncut read A2 instead of A (qkv fusion)
__global__ __launch_bounds__(256) void gemmb(
    const unsigned short* __restrict__ A,   // [M][K] bf16
    const unsigned short* __restrict__ A2,
    int ncut,
    const unsigned short* __restrict__ Bt,  // [N][K] bf16
    const float* __restrict__ bias,
    float* __restrict__ Cf, unsigned short* __restrict__ Cb,
    int M, int K, int N, int relu){
  __shared__ unsigned short As[64][40];
  __shared__ unsigned short Bs[64][40];
  int n0 = blockIdx.x*64, m0 = blockIdx.y*64;
  const unsigned short* Asrc = (A2 && n0 >= ncut) ? A2 : A;
  int t = threadIdx.x, wave = t>>6, lane = t&63;
  int wm = (wave>>1)*32, wn = (wave&1)*32;
  int hi = lane>>4, lo = lane&15;
  int sr = t>>2, sc = (t&3)*8;
  f32x4 acc[2][2];
#pragma unroll
  for(int i=0;i<2;++i)
#pragma unroll
    for(int j=0;j<2;++j)
#pragma unroll
      for(int r=0;r<4;++r) acc[i][j][r]=0.f;
  for(int k0=0;k0<K;k0+=32){
    uint4 av = make_uint4(0,0,0,0);
    int arow = m0+sr;
    if(arow < M) av = *(const uint4*)(Asrc + (size_t)arow*K + k0 + sc);
    *(uint4*)&As[sr][sc] = av;
    *(uint4*)&Bs[sr][sc] = *(const uint4*)(Bt + (size_t)(n0+sr)*K + k0 + sc);
    __syncthreads();
    short8v a0 = *(short8v*)&As[wm+lo][hi*8];
    short8v a1 = *(short8v*)&As[wm+16+lo][hi*8];
    short8v b0 = *(short8v*)&Bs[wn+lo][hi*8];
    short8v b1 = *(short8v*)&Bs[wn+16+lo][hi*8];
    acc[0][0] = __builtin_amdgcn_mfma_f32_16x16x32_bf16(a0,b0,acc[0][0],0,0,0);
    acc[0][1] = __builtin_amdgcn_mfma_f32_16x16x32_bf16(a0,b1,acc[0][1],0,0,0);
    acc[1][0] = __builtin_amdgcn_mfma_f32_16x16x32_bf16(a1,b0,acc[1][0],0,0,0);
    acc[1][1] = __builtin_amdgcn_mfma_f32_16x16x32_bf16(a1,b1,acc[1][1],0,0,0);
    __syncthreads();
  }
#pragma unroll
  for(int mf=0;mf<2;++mf){
#pragma unroll
    for(int nf=0;nf<2;++nf){
      int col = n0 + wn + nf*16 + lo;
      float bv = bias[col];
#pragma unroll
      for(int r=0;r<4;++r){
        int row = m0 + wm + mf*16 + hi*4 + r;
        if(row < M){
          float v = acc[mf][nf][r] + bv;
          if(relu) v = fmaxf(v, 0.f);
          if(Cf) Cf[(size_t)row*N+col] = v;
          if(Cb) Cb[(size_t)row*N+col] = f2bf(v);
        }
      }
    }
  }
}

// ---------------- bf16 MFMA value GEMM (M=36864), 128x128 tile, bf16 out ----
__global__ __launch_bounds__(256) void mfma_value(
    const unsigned short* __restrict__ Abf,   // [M][256] bf16
    const unsigned short* __restrict__ Bt,    // [256][256] bf16, Bt[n][k]
    const float* __restrict__ bias, const unsigned char* __restrict__ rowmask,
    unsigned short* __restrict__ C){
  __shared__ unsigned short As[128][40];
  __shared__ unsigned short Bs[128][40];
  int m0 = blockIdx.x*128, n0 = blockIdx.y*128;
  int t = threadIdx.x;
  int wave = t>>6, lane = t&63;
  int wm = (wave>>1)*64, wn = (wave&1)*64;
  f32x4 acc[4][4];
#pragma unroll
  for(int i=0;i<4;++i)
#pragma unroll
    for(int j=0;j<4;++j)
#pragma unroll
      for(int r=0;r<4;++r) acc[i][j][r]=0.f;

  int r0 = t>>2, c0 = (t&3)*8;
  int r1 = (t+256)>>2;
  for(int k0=0;k0<256;k0+=32){
    *(uint4*)&As[r0][c0] = *(const uint4*)(Abf + (size_t)(m0+r0)*256 + k0 + c0);
    *(uint4*)&As[r1][c0] = *(const uint4*)(Abf + (size_t)(m0+r1)*256 + k0 + c0);
    *(uint4*)&Bs[r0][c0] = *(const uint4*)(Bt  + (size_t)(n0+r0)*256 + k0 + c0);
    *(uint4*)&Bs[r1][c0] = *(const uint4*)(Bt  + (size_t)(n0+r1)*256 + k0 + c0);
    __syncthreads();
    short8v a[4], bb[4];
#pragma unroll
    for(int mf=0;mf<4;++mf) a[mf]  = *(short8v*)&As[wm+mf*16+(lane&15)][(lane>>4)*8];
#pragma unroll
    for(int nf=0;nf<4;++nf) bb[nf] = *(short8v*)&Bs[wn+nf*16+(lane&15)][(lane>>4)*8];
#pragma unroll
    for(int mf=0;mf<4;++mf)
#pragma unroll
      for(int nf=0;nf<4;++nf)
        acc[mf][nf] = __builtin_amdgcn_mfma_f32_16x16x32_bf16(a[mf], bb[nf], acc[mf][nf], 0,0,0);
    __syncthreads();
  }
#pragma unroll
  for(int mf=0;mf<4;++mf){
    int rbase = m0 + wm + mf*16 + (lane>>4)*4;
#pragma unroll
    for(int nf=0;nf<4;++nf){
      int col = n0 + wn + nf*16 + (lane&15);
      float bv = bias[col];
#pragma unroll
      for(int r=0;r<4;++r){
        int row = rbase + r;
        float v = acc[mf][nf][r] + bv;
        if(rowmask[row]) v = 0.f;
        C[(size_t)row*256 + col] = f2bf(v);
      }
    }
  }
}

// ---------------- MFMA self attention: block = (b,h) x 64-row Q tile --------
__global__ __launch_bounds__(256) void self_attn_mfma(
    const unsigned short* __restrict__ qkvh, // [1200][768] bf16 (q|k|v)
    unsigned short* __restrict__ sa){        // [1200][256] bf16
  __shared__ unsigned short P[64][328];
  __shared__ unsigned short Vt[32][328];
  int blk = blockIdx.x;
  int qt = blk % 5; int bh = blk / 5; int h = bh % NHD; int b = bh / NHD;
  int t = threadIdx.x, wv = t>>6, lane = t&63;
  int hi = lane>>4, lo = lane&15;
  // stage Vt[c][k] = v[b*300+k][h*32+c], zero-pad k>=300
  {
    int c = t & 31, rb = t >> 5;
    for(int r = rb; r < 320; r += 8){
      unsigned short v = 0;
      if(r < 300) v = qkvh[(size_t)(b*300+r)*768 + 512 + h*32 + c];
      Vt[c][r] = v;
    }
  }
  __syncthreads();
  int m0 = qt*64 + wv*16;
  int qr = m0 + lo; if(qr > 299) qr = 299;
  short8v aq = *(const short8v*)(qkvh + (size_t)(b*300+qr)*768 + h*32 + hi*8);
  f32x4 s[19];
#pragma unroll
  for(int nt=0; nt<19; ++nt){
    int kr = nt*16 + lo; if(kr > 299) kr = 299;
    short8v bk = *(const short8v*)(qkvh + (size_t)(b*300+kr)*768 + 256 + h*32 + hi*8);
    f32x4 z; z[0]=0.f; z[1]=0.f; z[2]=0.f; z[3]=0.f;
    s[nt] = __builtin_amdgcn_mfma_f32_16x16x32_bf16(aq, bk, z, 0,0,0);
  }
  const float kSc = 0.25506009837f;   // (1/sqrt(32)) * log2(e)
  float inv[4];
#pragma unroll
  for(int ri=0; ri<4; ++ri){
    float m = -1e30f;
#pragma unroll
    for(int nt=0; nt<19; ++nt){
      if(nt*16+lo < 300) m = fmaxf(m, s[nt][ri]);
    }
#pragma unroll
    for(int o=8;o>=1;o>>=1) m = fmaxf(m, __shfl_xor(m,o,64));
    float sum = 0.f;
#pragma unroll
    for(int nt=0; nt<19; ++nt){
      float p = 0.f;
      if(nt*16+lo < 300) p = exp2f((s[nt][ri]-m)*kSc);
      sum += p;
      P[wv*16 + hi*4 + ri][nt*16 + lo] = f2bf(p);
    }
    P[wv*16 + hi*4 + ri][304 + lo] = 0;
#pragma unroll
    for(int o=8;o>=1;o>>=1) sum += __shfl_xor(sum,o,64);
    inv[ri] = 1.f/sum;
  }
  f32x4 o0, o1;
#pragma unroll
  for(int r=0;r<4;++r){ o0[r]=0.f; o1[r]=0.f; }
#pragma unroll
  for(int kt=0; kt<10; ++kt){
    short8v ap = *(short8v*)&P[wv*16 + lo][kt*32 + hi*8];
    short8v b0 = *(short8v*)&Vt[lo][kt*32 + hi*8];
    short8v b1 = *(short8v*)&Vt[16+lo][kt*32 + hi*8];
    o0 = __builtin_amdgcn_mfma_f32_16x16x32_bf16(ap, b0, o0, 0,0,0);
    o1 = __builtin_amdgcn_mfma_f32_16x16x32_bf16(ap, b1, o1, 0,0,0);
  }
#pragma unroll
  for(int ri=0; ri<4; ++ri){
    int r = m0 + hi*4 + ri;
    if(r < 300){
      size_t base = (size_t)(b*300+r)*256 + h*32;
      sa[base + lo]      = f2bf(o0[ri]*inv[ri]);
      sa[base + 16 + lo] = f2bf(o1[ri]*inv[ri]);
    }
  }
}

// ---------------- residual + layernorm (+ optional bf16 emissions) ----------
__global__ void residual_ln(const float* __restrict__ base, const float* __restrict__ delta,
                            const float* __restrict__ w, const float* __restrict__ bvec,
                            float* __restrict__ dstf, unsigned short* __restrict__ dstb,
                            unsigned short* __restrict__ dstp, const float* __restrict__ qe){
  __shared__ float red[4];
  size_t row = blockIdx.x; int t = threadIdx.x;
  float v = base[row*D+t] + delta[row*D+t];
  float mean = bred_sum(v, red) * (1.f/D);
  float c = v - mean;
  float var = bred_sum(c*c, red) * (1.f/D);
  float y = c * rsqrtf(var + LNEPS) * w[t] + bvec[t];
  dstf[row*D+t] = y;
  if(dstb) dstb[row*D+t] = f2bf(y);
  if(dstp){
    int q = (int)(row % NQ);
    dstp[row*D+t] = f2bf(y + qe[(size_t)q*2*D + t]);
  }
}

// ---------------- fused deformable cross-attn (bf16 value, emits bf16) ------
__global__ void deform_attn(const float* __restrict__ outb, const float* __restrict__ qe,
                            const float* __restrict__ offw, const float* __restrict__ offb,
                            const float* __restrict__ attnw, const float* __restrict__ attnb,
                            const unsigned short* __restrict__ value, const float* __restrict__ refp,
                            const float* __restrict__ vr, const int* __restrict__ sshape,
                            unsigned short* __restrict__ ca){
  __shared__ float qrow[D];
  __shared__ float part[96][2];
  __shared__ float proj[96];
  int row = blockIdx.x; int b = row / NQ; int q = row % NQ;
  int t = threadIdx.x;
  qrow[t] = outb[(size_t)row*D + t] + qe[(size_t)q*2*D + t];
  __syncthreads();
  if(t < 192){
    int col = t >> 1, half = t & 1;
    float acc = 0.f;
    if(col < 64){
      const float* W = offw;
      for(int k=half*128; k<half*128+128; ++k) acc += qrow[k]*W[(size_t)k*64 + col];
    } else {
      const float* W = attnw; int c = col-64;
      for(int k=half*128; k<half*128+128; ++k) acc += qrow[k]*W[(size_t)k*32 + c];
    }
    part[col][half] = acc;
  }
  __syncthreads();
  if(t < 96) proj[t] = part[t][0] + part[t][1] + (t<64 ? offb[t] : attnb[t-64]);
  __syncthreads();

  int h = t>>5, hd = t&31;
  float Hf = (float)sshape[0], Wf = (float)sshape[1];
  int Ws = sshape[1];
  float rx = refp[q*2+0] * vr[b*2+0];
  float ry = refp[q*2+1] * vr[b*2+1];
  const float* lg = &proj[64 + h*4];
  float m = fmaxf(fmaxf(lg[0],lg[1]),fmaxf(lg[2],lg[3]));
  float e[4]; float esum=0.f;
#pragma unroll
  for(int p=0;p<4;++p){ e[p]=expf(lg[p]-m); esum+=e[p]; }
  float einv = 1.f/esum;
  const float* ofr = &proj[h*8];
  const unsigned short* vbase = value + ((size_t)b*NSRC)*D + h*HDIM + hd;
  float acc = 0.f;
#pragma unroll
  for(int p=0;p<NPTS;++p){
    float lx = rx + ofr[p*2+0]/Wf;
    float ly = ry + ofr[p*2+1]/Hf;
    float x = lx*Wf - 0.5f, y = ly*Hf - 0.5f;
    float x0 = floorf(x), y0 = floorf(y);
    float wx = x-x0, wy = y-y0;
    float sample = 0.f;
#pragma unroll
    for(int cy=0;cy<2;++cy){
#pragma unroll
      for(int cx=0;cx<2;++cx){
        float xi = x0+cx, yi = y0+cy;
        float wgt = (cx? wx : 1.f-wx) * (cy? wy : 1.f-wy);
        bool valid = (xi>=0.f)&&(xi<=Wf-1.f)&&(yi>=0.f)&&(yi<=Hf-1.f);
        if(valid){
          int idx = (int)fminf(fmaxf(yi,0.f),Hf-1.f)*Ws + (int)fminf(fmaxf(xi,0.f),Wf-1.f);
          sample += wgt * bf2f(vbase[(size_t)idx*D]);
        }
      }
    }
    acc += (e[p]*einv) * sample;
  }
  ca[(size_t)row*D + h*HDIM + hd] = f2bf(acc);
}

// ---------------- host ----------------
extern "C" void kernel_launch(void* const* d_in, const int* in_sizes, int n_in,
                              void* d_out, int out_size, void* d_ws, size_t ws_size,
                              hipStream_t stream){
  const float* aps=(const float*)d_in[0];
  const float* dvs=(const float*)d_in[1];
  const float* qe =(const float*)d_in[2];
  const float* vr =(const float*)d_in[3];
  const float* aps_w1=(const float*)d_in[4]; const float* aps_b1=(const float*)d_in[5];
  const float* aps_w2=(const float*)d_in[6]; const float* aps_b2=(const float*)d_in[7];
  const float* dvs_w1=(const float*)d_in[8]; const float* dvs_b1=(const float*)d_in[9];
  const float* dvs_w2=(const float*)d_in[10]; const float* dvs_b2=(const float*)d_in[11];
  const float* ref_w=(const float*)d_in[12]; const float* ref_b=(const float*)d_in[13];
  const float* saqkvw=(const float*)d_in[14]; const float* saqkvb=(const float*)d_in[15];
  const float* saoutw=(const float*)d_in[16]; const float* saoutb=(const float*)d_in[17];
  const float* offw=(const float*)d_in[18]; const float* offb=(const float*)d_in[19];
  const float* attnw=(const float*)d_in[20]; const float* attnb=(const float*)d_in[21];
  const float* valw=(const float*)d_in[22]; const float* valb=(const float*)d_in[23];
  const float* coutw=(const float*)d_in[24]; const float* coutb=(const float*)d_in[25];
  const float* ln1w=(const float*)d_in[26]; const float* ln1b=(const float*)d_in[27];
  const float* ln2w=(const float*)d_in[28]; const float* ln2b=(const float*)d_in[29];
  const float* ln3w=(const float*)d_in[30]; const float* ln3b=(const float*)d_in[31];
  const float* ffw1=(const float*)d_in[32]; const float* ffb1=(const float*)d_in[33];
  const float* ffw2=(const float*)d_in[34]; const float* ffb2=(const float*)d_in[35];
  const unsigned char* mask=(const unsigned char*)d_in[36];
  const int* sshape=(const int*)d_in[37];
  float* out = (float*)d_out;

  char* wsb = (char*)d_ws;
  size_t o = 0;
  unsigned short* srcb   = (unsigned short*)(wsb+o); o += (size_t)NVROWS*D*2;
  unsigned short* valT   = (unsigned short*)(wsb+o); o += (size_t)NLAY*D*D*2;
  unsigned short* qkvT   = (unsigned short*)(wsb+o); o += (size_t)NLAY*3*D*D*2;
  unsigned short* saoutT = (unsigned short*)(wsb+o); o += (size_t)NLAY*D*D*2;
  unsigned short* coutT  = (unsigned short*)(wsb+o); o += (size_t)NLAY*D*D*2;
  unsigned short* ff1T   = (unsigned short*)(wsb+o); o += (size_t)NLAY*D*FFD*2;
  unsigned short* ff2T   = (unsigned short*)(wsb+o); o += (size_t)NLAY*FFD*D*2;
  unsigned short* value  = (unsigned short*)(wsb+o); o += (size_t)NVROWS*D*2;
  float* pA    = (float*)(wsb+o); o += BSZ*CHK*D*4;
  float* pD    = (float*)(wsb+o); o += BSZ*CHK*D*4;
  float* s2    = (float*)(wsb+o); o += 2*BSZ*D*4;
  float* tA    = (float*)(wsb+o); o += BSZ*D*4;
  float* tD    = (float*)(wsb+o); o += BSZ*D*4;
  float* cAB   = (float*)(wsb+o); o += 16*4;
  float* refp  = (float*)(wsb+o); o += NQ*2*4;
  float* outb  = (float*)(wsb+o); o += (size_t)NROWS*D*4;
  float* tmpb  = (float*)(wsb+o); o += (size_t)NROWS*D*4;
  unsigned short* out_bf    = (unsigned short*)(wsb+o); o += (size_t)NROWS*D*2;
  unsigned short* outpos_bf = (unsigned short*)(wsb+o); o += (size_t)NROWS*D*2;
  unsigned short* qkvh_bf   = (unsigned short*)(wsb+o); o += (size_t)NROWS*3*D*2;
  unsigned short* sa_bf     = (unsigned short*)(wsb+o); o += (size_t)NROWS*D*2;
  unsigned short* ca_bf     = (unsigned short*)(wsb+o); o += (size_t)NROWS*D*2;
  unsigned short* ffh_bf    = (unsigned short*)(wsb+o); o += (size_t)NROWS*FFD*2;

  // ---- prologue
  colsum_partial<<<BSZ*CHK,256,0,stream>>>(aps,dvs,pA,pD);
  gate_s2<<<2*BSZ,256,0,stream>>>(pA,pD,aps_w2,aps_b2,dvs_w2,dvs_b2,aps_b1,dvs_b1,s2,cAB);
  gate_t<<<512,256,0,stream>>>(aps_w1,dvs_w1,s2,tA,tD);
  gate_src<<<NVROWS/4,256,0,stream>>>(aps,dvs,tA,tD,cAB,srcb);
  wconvT<<<dim3(8*8,  NLAY),256,0,stream>>>(valw,   valT,   D, D);
  wconvT<<<dim3(8*24, NLAY),256,0,stream>>>(saqkvw, qkvT,   D, 3*D);
  wconvT<<<dim3(8*8,  NLAY),256,0,stream>>>(saoutw, saoutT, D, D);
  wconvT<<<dim3(8*8,  NLAY),256,0,stream>>>(coutw,  coutT,  D, D);
  wconvT<<<dim3(8*32, NLAY),256,0,stream>>>(ffw1,   ff1T,   D, FFD);
  wconvT<<<dim3(32*8, NLAY),256,0,stream>>>(ffw2,   ff2T,   FFD, D);
  init_out_ref<<<NQ,256,0,stream>>>(qe,ref_w,ref_b,outb,out_bf,outpos_bf,refp,out);

  dim3 gqkv(12,19), g256(4,19), gffu(16,19);
  dim3 gmv(NVROWS/128,2);

  for(int l=0;l<NLAY;++l){
    const unsigned short* qkvTl = qkvT + (size_t)l*3*D*D;
    const float* bqkv = saqkvb + (size_t)l*3*D;
    // self attention: q,k from out+qpos, v from out — one fused GEMM (N=768)
    gemmb<<<gqkv,256,0,stream>>>(outpos_bf, out_bf, 512, qkvTl, bqkv,
                                 nullptr, qkvh_bf, NROWS, D, 3*D, 0);
    self_attn_mfma<<<BSZ*NHD*5,256,0,stream>>>(qkvh_bf, sa_bf);
    gemmb<<<g256,256,0,stream>>>(sa_bf, nullptr, 0, saoutT+(size_t)l*D*D, saoutb+(size_t)l*D,
                                 tmpb, nullptr, NROWS, D, D, 0);
    residual_ln<<<NROWS,256,0,stream>>>(outb,tmpb,ln2w+(size_t)l*D,ln2b+(size_t)l*D, outb,nullptr,nullptr,qe);

    // deformable cross attention
    mfma_value<<<gmv,256,0,stream>>>(srcb, valT+(size_t)l*D*D, valb+(size_t)l*D, mask, value);
    deform_attn<<<NROWS,256,0,stream>>>(outb,qe,
                                        offw+(size_t)l*D*64, offb+(size_t)l*64,
                                        attnw+(size_t)l*D*32, attnb+(size_t)l*32,
                                        value,refp,vr,sshape,ca_bf);
    gemmb<<<g256,256,0,stream>>>(ca_bf, nullptr, 0, coutT+(size_t)l*D*D, coutb+(size_t)l*D,
                                 tmpb, nullptr, NROWS, D, D, 0);
    residual_ln<<<NROWS,256,0,stream>>>(outb,tmpb,ln1w+(size_t)l*D,ln1b+(size_t)l*D, outb,out_bf,nullptr,qe);

    // FFN
    gemmb<<<gffu,256,0,stream>>>(out_bf, nullptr, 0, ff1T+(size_t)l*D*FFD, ffb1+(size_t)l*FFD,
                                 nullptr, ffh_bf, NROWS, D, FFD, 1);
    gemmb<<<g256,256,0,stream>>>(ffh_bf, nullptr, 0, ff2T+(size_t)l*FFD*D, ffb2+(size_t)l*D,
                                 tmpb, nullptr, NROWS, FFD, D, 0);
    if(l==NLAY-1)
      residual_ln<<<NROWS,256,0,stream>>>(outb,tmpb,ln3w+(size_t)l*D,ln3b+(size_t)l*D, out,nullptr,nullptr,qe);
    else
      residual_ln<<<NROWS,256,0,stream>>>(outb,tmpb,ln3w+(size_t)l*D,ln3b+(size_t)l*D, outb,out_bf,outpos_bf,qe);
  }
}